// Round 10
// baseline (441.460 us; speedup 1.0000x reference)
//
#include <hip/hip_runtime.h>

typedef __attribute__((ext_vector_type(8))) short bf16x8;
typedef __attribute__((ext_vector_type(8))) unsigned short ushort8;
typedef __attribute__((ext_vector_type(4))) float f32x4;

#define NN 50000
#define HH 128

static __device__ __forceinline__ unsigned short f2bf(float f) {
  unsigned u = __builtin_bit_cast(unsigned, f);
  u = u + 0x7FFFu + ((u >> 16) & 1u);
  return (unsigned short)(u >> 16);
}

static __device__ __forceinline__ float bf2f(unsigned short b) {
  return __builtin_bit_cast(float, ((unsigned)b) << 16);
}

static __device__ __forceinline__ bf16x8 bfrag(const unsigned short* __restrict__ w,
                                               int kt, int nt, int lane) {
  return *reinterpret_cast<const bf16x8*>(w + (((kt * 8 + nt) * 64 + lane) << 3));
}

// Fused weight swizzle: 10 jobs with K=128 (64 blocks each), 2 jobs with K=512 (256 blocks).
struct SwzJobs {
  const float* src[12];
  unsigned short* dst[12];
};
__global__ void swz_all_kernel(SwzJobs jobs) {
  int b = blockIdx.x;
  int job, blk;
  if (b < 640) { job = b >> 6; blk = b & 63; }
  else { b -= 640; job = 10 + (b >> 8); blk = b & 255; }
  int o = blk * 256 + threadIdx.x;
  int j = o & 7, lane = (o >> 3) & 63, nt = (o >> 9) & 7, kt = o >> 12;
  int row = kt * 32 + (lane >> 4) * 8 + j;
  int col = nt * 16 + (lane & 15);
  jobs.dst[job][o] = f2bf(jobs.src[job][row * 128 + col]);
}

// 6-job K=128 swizzle (for combined weights)
struct Swz6 {
  const float* src[6];
  unsigned short* dst[6];
};
__global__ void swz6_kernel(Swz6 jobs) {
  int b = blockIdx.x;
  int job = b >> 6, blk = b & 63;
  int o = blk * 256 + threadIdx.x;
  int j = o & 7, lane = (o >> 3) & 63, nt = (o >> 9) & 7, kt = o >> 12;
  int row = kt * 32 + (lane >> 4) * 8 + j;
  int col = nt * 16 + (lane & 15);
  jobs.dst[job][o] = f2bf(jobs.src[job][row * 128 + col]);
}

// Combined weights: C = W2_s(f32,row-major) @ {Wg|Wu1}[128(s+1):...] -> f32 row-major.
struct CmbJobs {
  const float* Af[6];
  const unsigned short* Bswz[6];
  int koff[6];
  float* Of[6];
};
__global__ __launch_bounds__(256) void cmb_kernel(CmbJobs jobs) {
  const int b = blockIdx.x;            // 12 blocks
  const int jb = b >> 1, half = b & 1;
  const int t = threadIdx.x;
  const int wave = t >> 6, lane = t & 63;
  const int lr = lane & 15, lgp = lane >> 4;
  const int rowbase = half * 64 + wave * 16;
  const float* A = jobs.Af[jb];
  f32x4 acc[8];
#pragma unroll
  for (int nt = 0; nt < 8; ++nt) acc[nt] = (f32x4){0.f, 0.f, 0.f, 0.f};
#pragma unroll
  for (int kt = 0; kt < 4; ++kt) {
    const float* ap = A + (rowbase + lr) * 128 + kt * 32 + lgp * 8;
    bf16x8 a;
#pragma unroll
    for (int j = 0; j < 8; ++j) a[j] = (short)f2bf(ap[j]);
#pragma unroll
    for (int nt = 0; nt < 8; ++nt)
      acc[nt] = __builtin_amdgcn_mfma_f32_16x16x32_bf16(
          a, bfrag(jobs.Bswz[jb], jobs.koff[jb] + kt, nt, lane), acc[nt], 0, 0, 0);
  }
  float* O = jobs.Of[jb];
#pragma unroll
  for (int nt = 0; nt < 8; ++nt) {
    int col = nt * 16 + lr;
#pragma unroll
    for (int rr = 0; rr < 4; ++rr)
      O[(rowbase + lgp * 4 + rr) * 128 + col] = acc[nt][rr];
  }
}

// Bias projections: c[col] = sum_k b2[k] * W[(off+k)*128 + col]
struct BiasJobs {
  const float* W[6];
  const float* b2[6];
  int off[6];
  float* out[6];
};
__global__ void bias_kernel(BiasJobs jobs) {
  const int jb = blockIdx.x;           // 6 blocks x 128 threads
  const int col = threadIdx.x;
  const float* W = jobs.W[jb];
  const float* b = jobs.b2[jb];
  const int off = jobs.off[jb];
  float c = 0.f;
  for (int k = 0; k < 128; ++k) c += b[k] * W[(off + k) * 128 + col];
  jobs.out[jb][col] = c;
}

// P/Q precompute: 6 GEMMs out = x @ W (+bias), bf16 row-major output; also writes xb.
struct PQJobs {
  const unsigned short* Wswz[6];
  const float* bias[6];
  unsigned short* out[6];
};
__global__ __launch_bounds__(256) void pq_kernel(const float* __restrict__ x,
                                                 unsigned short* __restrict__ xb,
                                                 PQJobs jobs) {
  __shared__ unsigned short As[64][136];
  const int t = threadIdx.x;
  const int n0 = blockIdx.x * 64;
  for (int idx = t; idx < 64 * 32; idx += 256) {
    int e = idx >> 5, c4 = (idx & 31) << 2;
    int row = n0 + e;
    float4 v = make_float4(0.f, 0.f, 0.f, 0.f);
    if (row < NN) v = *reinterpret_cast<const float4*>(x + (long)row * HH + c4);
    *reinterpret_cast<ushort4*>(&As[e][c4]) =
        make_ushort4(f2bf(v.x), f2bf(v.y), f2bf(v.z), f2bf(v.w));
  }
  __syncthreads();
  for (int idx = t; idx < 64 * 32; idx += 256) {
    int e = idx >> 5, c4 = (idx & 31) << 2;
    int row = n0 + e;
    if (row < NN)
      *reinterpret_cast<ushort4*>(xb + (long)row * HH + c4) =
          *reinterpret_cast<const ushort4*>(&As[e][c4]);
  }
  const int wave = t >> 6, lane = t & 63;
  const int lr = lane & 15, lgp = lane >> 4;
  bf16x8 afr[4];
#pragma unroll
  for (int kt = 0; kt < 4; ++kt)
    afr[kt] = *reinterpret_cast<const bf16x8*>(&As[wave * 16 + lr][kt * 32 + lgp * 8]);
#pragma unroll
  for (int jb = 0; jb < 6; ++jb) {
    f32x4 acc[8];
#pragma unroll
    for (int nt = 0; nt < 8; ++nt) acc[nt] = (f32x4){0.f, 0.f, 0.f, 0.f};
#pragma unroll
    for (int kt = 0; kt < 4; ++kt)
#pragma unroll
      for (int nt = 0; nt < 8; ++nt)
        acc[nt] = __builtin_amdgcn_mfma_f32_16x16x32_bf16(
            afr[kt], bfrag(jobs.Wswz[jb], kt, nt, lane), acc[nt], 0, 0, 0);
    const float* bi = jobs.bias[jb];
    unsigned short* O = jobs.out[jb];
#pragma unroll
    for (int nt = 0; nt < 8; ++nt) {
      int col = nt * 16 + lr;
      float bv = bi ? bi[col] : 0.f;
#pragma unroll
      for (int r = 0; r < 4; ++r) {
        int row = n0 + wave * 16 + lgp * 4 + r;
        if (row < NN) O[(long)row * HH + col] = f2bf(acc[nt][r] + bv);
      }
    }
  }
}

// ---- counting-sort by destination (two-level parallel scan) ----
__global__ void hist3_kernel(const int* __restrict__ eiL, const int* __restrict__ eiM,
                             const int* __restrict__ eiG, int El, int Em, int Eg,
                             int* __restrict__ cnt) {
  int e = blockIdx.x * 256 + threadIdx.x;
  const int* ei; int E, off;
  if (e < El) { ei = eiL; E = El; off = 0; }
  else if (e < El + Em) { e -= El; ei = eiM; E = Em; off = NN; }
  else { e -= El + Em; if (e >= Eg) return; ei = eiG; E = Eg; off = 2 * NN; }
  atomicAdd(cnt + off + ei[E + e], 1);
}

__global__ void scanA_kernel(const int* __restrict__ cnt, int* __restrict__ offs,
                             int* __restrict__ bsum, int n) {
  const int t = threadIdx.x, lane = t & 63, w = t >> 6;
  const int i = blockIdx.x * 1024 + t;
  __shared__ int wsum[16], wpre[16];
  int v = (i < n) ? cnt[i] : 0;
  int inc = v;
#pragma unroll
  for (int d = 1; d < 64; d <<= 1) {
    int o = __shfl_up(inc, d, 64);
    if (lane >= d) inc += o;
  }
  if (lane == 63) wsum[w] = inc;
  __syncthreads();
  if (t == 0) {
    int run = 0;
#pragma unroll
    for (int k = 0; k < 16; ++k) { wpre[k] = run; run += wsum[k]; }
    wsum[0] = run;
  }
  __syncthreads();
  if (i < n) offs[i] = wpre[w] + inc - v;
  if (t == 0) bsum[blockIdx.x] = wsum[0];
}

__global__ void scanB_kernel(int* __restrict__ bsum, int n) {
  const int t = threadIdx.x, lane = t & 63, w = t >> 6;
  __shared__ int wsum[4];
  int v = (t < n) ? bsum[t] : 0;
  int inc = v;
#pragma unroll
  for (int d = 1; d < 64; d <<= 1) {
    int o = __shfl_up(inc, d, 64);
    if (lane >= d) inc += o;
  }
  if (lane == 63) wsum[w] = inc;
  __syncthreads();
  int wo = 0;
  for (int k = 0; k < w; ++k) wo += wsum[k];
  if (t < n) bsum[t] = wo + inc - v;
}

__global__ void scanC_kernel(int* __restrict__ offs, int* __restrict__ rowptr,
                             const int* __restrict__ bsum, int n) {
  int i = blockIdx.x * 1024 + threadIdx.x;
  if (i < n) {
    int v = offs[i] + bsum[blockIdx.x];
    offs[i] = v;
    rowptr[i] = v;
  }
}

// Scatter: packed 16B record {src_bits, ea0, ea1, ea2} at dst-sorted position.
__global__ void scatter3_kernel(const int* __restrict__ eiL, const int* __restrict__ eiM,
                                const int* __restrict__ eiG,
                                const float* __restrict__ eaL, const float* __restrict__ eaM,
                                const float* __restrict__ eaG,
                                int El, int Em, int Eg, int* __restrict__ offs,
                                float4* __restrict__ sed) {
  int e = blockIdx.x * 256 + threadIdx.x;
  const int* ei; const float* ea; int E, off;
  if (e < El) { ei = eiL; ea = eaL; E = El; off = 0; }
  else if (e < El + Em) { e -= El; ei = eiM; ea = eaM; E = Em; off = NN; }
  else { e -= El + Em; if (e >= Eg) return; ei = eiG; ea = eaG; E = Eg; off = 2 * NN; }
  int d = ei[E + e];
  int p = atomicAdd(offs + off + d, 1);
  sed[p] = make_float4(__int_as_float(ei[e]),
                       ea[(long)e * 3 + 0], ea[(long)e * 3 + 1], ea[(long)e * 3 + 2]);
}

// ---- edge kernel: one WAVE per dst (CSR run), scalarized metadata.
// hagg[dst] = bf16(sum relu(P[src]+Q[dst]+ea.Wc)). Plain stores, no atomics/LDS/barriers.
struct EScale2 { const unsigned short *P, *Q; const float* Wc; unsigned short* hag; };
struct EParams2 {
  EScale2 s[3];
  const float4* sed;
  const int* rowptr; const int* cnt;
};
__global__ __launch_bounds__(256) void edge_kernel(EParams2 prm) {
  const int t = threadIdx.x;
  const int wave = t >> 6, lane = t & 63;
  int gidv = blockIdx.x * 4 + wave;
  if (gidv >= 3 * NN) return;
  const int gid = __builtin_amdgcn_readfirstlane(gidv);
  const int si = (gid >= NN) + (gid >= 2 * NN);
  const int dst = gid - si * NN;
  const EScale2 S = prm.s[si];
  const int base = __builtin_amdgcn_readfirstlane(prm.rowptr[gid]);
  const int len = __builtin_amdgcn_readfirstlane(prm.cnt[gid]);
  const int c2 = lane * 2;

  const float wcA0 = S.Wc[c2],       wcB0 = S.Wc[c2 + 1];
  const float wcA1 = S.Wc[128 + c2], wcB1 = S.Wc[129 + c2];
  const float wcA2 = S.Wc[256 + c2], wcB2 = S.Wc[257 + c2];

  float aA0 = 0.f, aB0 = 0.f, aA1 = 0.f, aB1 = 0.f;
  if (len > 0) {
    ushort2 qv = *reinterpret_cast<const ushort2*>(S.Q + (long)dst * HH + c2);
    const float qA = bf2f(qv.x), qB = bf2f(qv.y);
    const float4* __restrict__ ep = prm.sed + base;
    int i = 0;
    for (; i + 4 <= len; i += 4) {
      float4 m0 = ep[i], m1 = ep[i + 1], m2 = ep[i + 2], m3 = ep[i + 3];
      ushort2 p0 = *reinterpret_cast<const ushort2*>(S.P + (long)__float_as_int(m0.x) * HH + c2);
      ushort2 p1 = *reinterpret_cast<const ushort2*>(S.P + (long)__float_as_int(m1.x) * HH + c2);
      ushort2 p2 = *reinterpret_cast<const ushort2*>(S.P + (long)__float_as_int(m2.x) * HH + c2);
      ushort2 p3 = *reinterpret_cast<const ushort2*>(S.P + (long)__float_as_int(m3.x) * HH + c2);
      aA0 += fmaxf(bf2f(p0.x) + qA + m0.y * wcA0 + m0.z * wcA1 + m0.w * wcA2, 0.f);
      aB0 += fmaxf(bf2f(p0.y) + qB + m0.y * wcB0 + m0.z * wcB1 + m0.w * wcB2, 0.f);
      aA1 += fmaxf(bf2f(p1.x) + qA + m1.y * wcA0 + m1.z * wcA1 + m1.w * wcA2, 0.f);
      aB1 += fmaxf(bf2f(p1.y) + qB + m1.y * wcB0 + m1.z * wcB1 + m1.w * wcB2, 0.f);
      aA0 += fmaxf(bf2f(p2.x) + qA + m2.y * wcA0 + m2.z * wcA1 + m2.w * wcA2, 0.f);
      aB0 += fmaxf(bf2f(p2.y) + qB + m2.y * wcB0 + m2.z * wcB1 + m2.w * wcB2, 0.f);
      aA1 += fmaxf(bf2f(p3.x) + qA + m3.y * wcA0 + m3.z * wcA1 + m3.w * wcA2, 0.f);
      aB1 += fmaxf(bf2f(p3.y) + qB + m3.y * wcB0 + m3.z * wcB1 + m3.w * wcB2, 0.f);
    }
    for (; i < len; ++i) {
      float4 m0 = ep[i];
      ushort2 p0 = *reinterpret_cast<const ushort2*>(S.P + (long)__float_as_int(m0.x) * HH + c2);
      aA0 += fmaxf(bf2f(p0.x) + qA + m0.y * wcA0 + m0.z * wcA1 + m0.w * wcA2, 0.f);
      aB0 += fmaxf(bf2f(p0.y) + qB + m0.y * wcB0 + m0.z * wcB1 + m0.w * wcB2, 0.f);
    }
  }
  *reinterpret_cast<ushort2*>(S.hag + (long)dst * HH + c2) =
      make_ushort2(f2bf(aA0 + aA1), f2bf(aB0 + aB1));
}

// ---- node kernel: A-stream [xb|hl|hm|hg] with combined weights + deg rank-1 epilogue ----
struct NodeParams {
  const float* x; const unsigned short* xb;
  const unsigned short* h[3];
  const int* cnt;
  const unsigned short* BG[4];   // Wg(K512 swz), W2gL, W2gM, W2gG
  const unsigned short* BU[4];   // Wu1(K512 swz), W2uL, W2uM, W2uG
  const float* cg;               // [3][128]
  const float* cu;               // [3][128]
  const unsigned short* Wu2;
  const float *bg, *bu1, *bu2, *gamma, *beta;
  float* out;
};
__global__ __launch_bounds__(256) void node_kernel(NodeParams p) {
  __shared__ unsigned short Hs[64][136];
  const int t = threadIdx.x;
  const int n0 = blockIdx.x * 64;
  const int wave = t >> 6, lane = t & 63;
  const int lr = lane & 15, lgp = lane >> 4;

  f32x4 accG[8], accH[8];
#pragma unroll
  for (int nt = 0; nt < 8; ++nt) {
    accG[nt] = (f32x4){0.f, 0.f, 0.f, 0.f};
    accH[nt] = (f32x4){0.f, 0.f, 0.f, 0.f};
  }
  const int arow = n0 + wave * 16 + lr;
  const bool aok = arow < NN;

#pragma unroll
  for (int kt = 0; kt < 16; ++kt) {
    const int chunk = kt >> 2;
    const unsigned short* S = (chunk == 0) ? p.xb : p.h[chunk - 1];
    const unsigned short* BG = p.BG[chunk];
    const unsigned short* BU = p.BU[chunk];
    int ktl = kt & 3;
    int cb = (ktl << 5) + (lgp << 3);
    bf16x8 a = (bf16x8){0, 0, 0, 0, 0, 0, 0, 0};
    if (aok) a = *reinterpret_cast<const bf16x8*>(S + (long)arow * HH + cb);
#pragma unroll
    for (int nt = 0; nt < 8; ++nt) {
      accG[nt] = __builtin_amdgcn_mfma_f32_16x16x32_bf16(a, bfrag(BG, ktl, nt, lane), accG[nt], 0, 0, 0);
      accH[nt] = __builtin_amdgcn_mfma_f32_16x16x32_bf16(a, bfrag(BU, ktl, nt, lane), accH[nt], 0, 0, 0);
    }
  }

  // degrees per row (3 scales)
  float dl[4], dm[4], dgg[4];
#pragma unroll
  for (int r = 0; r < 4; ++r) {
    int row = n0 + wave * 16 + lgp * 4 + r;
    bool ok = row < NN;
    dl[r] = ok ? (float)p.cnt[row] : 0.f;
    dm[r] = ok ? (float)p.cnt[NN + row] : 0.f;
    dgg[r] = ok ? (float)p.cnt[2 * NN + row] : 0.f;
  }

#pragma unroll
  for (int nt = 0; nt < 8; ++nt) {
    int col = nt * 16 + lr;
    float bgv = p.bg[col], bhv = p.bu1[col];
    float cgl = p.cg[col], cgm = p.cg[128 + col], cgg = p.cg[256 + col];
    float cul = p.cu[col], cum = p.cu[128 + col], cug = p.cu[256 + col];
#pragma unroll
    for (int r = 0; r < 4; ++r) {
      float gpre = accG[nt][r] + bgv + dl[r] * cgl + dm[r] * cgm + dgg[r] * cgg;
      float g = 1.f / (1.f + __expf(-gpre));
      accG[nt][r] = g;
      float hpre = accH[nt][r] + bhv + dl[r] * cul + dm[r] * cum + dgg[r] * cug;
      Hs[wave * 16 + lgp * 4 + r][col] = f2bf(fmaxf(hpre, 0.f));
    }
  }

  f32x4 accU[8];
#pragma unroll
  for (int nt = 0; nt < 8; ++nt) accU[nt] = (f32x4){0.f, 0.f, 0.f, 0.f};
#pragma unroll
  for (int kt = 0; kt < 4; ++kt) {
    bf16x8 a = *reinterpret_cast<const bf16x8*>(&Hs[wave * 16 + lr][kt * 32 + lgp * 8]);
#pragma unroll
    for (int nt = 0; nt < 8; ++nt) {
      accU[nt] = __builtin_amdgcn_mfma_f32_16x16x32_bf16(a, bfrag(p.Wu2, kt, nt, lane), accU[nt], 0, 0, 0);
    }
  }

#pragma unroll
  for (int nt = 0; nt < 8; ++nt) {
    int col = nt * 16 + lr;
    float b2v = p.bu2[col];
#pragma unroll
    for (int r = 0; r < 4; ++r) {
      int row = n0 + wave * 16 + lgp * 4 + r;
      float xv = (row < NN) ? p.x[(long)row * HH + col] : 0.f;
      float u = accU[nt][r] + b2v;
      float g = accG[nt][r];
      accU[nt][r] = g * u + (1.f - g) * xv;
    }
  }

#pragma unroll
  for (int r = 0; r < 4; ++r) {
    int row = n0 + wave * 16 + lgp * 4 + r;
    float s = 0.f;
#pragma unroll
    for (int nt = 0; nt < 8; ++nt) s += accU[nt][r];
    s += __shfl_xor(s, 1, 64);
    s += __shfl_xor(s, 2, 64);
    s += __shfl_xor(s, 4, 64);
    s += __shfl_xor(s, 8, 64);
    float mu = s * (1.f / 128.f);
    float qv = 0.f;
#pragma unroll
    for (int nt = 0; nt < 8; ++nt) {
      float d = accU[nt][r] - mu;
      qv += d * d;
    }
    qv += __shfl_xor(qv, 1, 64);
    qv += __shfl_xor(qv, 2, 64);
    qv += __shfl_xor(qv, 4, 64);
    qv += __shfl_xor(qv, 8, 64);
    float rs = rsqrtf(qv * (1.f / 128.f) + 1e-5f);
    if (row < NN) {
#pragma unroll
      for (int nt = 0; nt < 8; ++nt) {
        int col = nt * 16 + lr;
        p.out[(long)row * HH + col] = (accU[nt][r] - mu) * rs * p.gamma[col] + p.beta[col];
      }
    }
  }
}

extern "C" void kernel_launch(void* const* d_in, const int* in_sizes, int n_in,
                              void* d_out, int out_size, void* d_ws, size_t ws_size,
                              hipStream_t stream) {
  const float* x = (const float*)d_in[0];
  const int* ei_l = (const int*)d_in[1];
  const float* ea_l = (const float*)d_in[2];
  const int* ei_m = (const int*)d_in[3];
  const float* ea_m = (const float*)d_in[4];
  const int* ei_g = (const int*)d_in[5];
  const float* ea_g = (const float*)d_in[6];
  const float* Wa1 = (const float*)d_in[7];
  const float* ba1 = (const float*)d_in[8];
  const float* Wa2 = (const float*)d_in[9];
  const float* ba2 = (const float*)d_in[10];
  const float* Wb1 = (const float*)d_in[11];
  const float* bb1 = (const float*)d_in[12];
  const float* Wb2 = (const float*)d_in[13];
  const float* bb2 = (const float*)d_in[14];
  const float* Wc1 = (const float*)d_in[15];
  const float* bc1 = (const float*)d_in[16];
  const float* Wc2 = (const float*)d_in[17];
  const float* bc2 = (const float*)d_in[18];
  const float* Wg = (const float*)d_in[19];
  const float* bg = (const float*)d_in[20];
  const float* Wu1 = (const float*)d_in[21];
  const float* bu1 = (const float*)d_in[22];
  const float* Wu2 = (const float*)d_in[23];
  const float* bu2 = (const float*)d_in[24];
  const float* gamma = (const float*)d_in[25];
  const float* beta = (const float*)d_in[26];

  const int El = in_sizes[1] / 2;
  const int Em = in_sizes[3] / 2;
  const int Eg = in_sizes[5] / 2;
  const int Etot = El + Em + Eg;

  // Workspace layout
  unsigned short* wp = (unsigned short*)d_ws;
  unsigned short* hl = wp; wp += (size_t)NN * HH;
  unsigned short* hm = wp; wp += (size_t)NN * HH;
  unsigned short* hg = wp; wp += (size_t)NN * HH;
  unsigned short* W1a_a = wp; wp += 128 * 128;
  unsigned short* W1b_a = wp; wp += 128 * 128;
  unsigned short* W1a_b = wp; wp += 128 * 128;
  unsigned short* W1b_b = wp; wp += 128 * 128;
  unsigned short* W1a_c = wp; wp += 128 * 128;
  unsigned short* W1b_c = wp; wp += 128 * 128;
  unsigned short* Wu2_s = wp; wp += 128 * 128;
  unsigned short* Wg_s  = wp; wp += 512 * 128;
  unsigned short* Wu1_s = wp; wp += 512 * 128;
  unsigned short* W2g_l = wp; wp += 128 * 128;   // combined, swizzled
  unsigned short* W2g_m = wp; wp += 128 * 128;
  unsigned short* W2g_g = wp; wp += 128 * 128;
  unsigned short* W2u_l = wp; wp += 128 * 128;
  unsigned short* W2u_m = wp; wp += 128 * 128;
  unsigned short* W2u_g = wp; wp += 128 * 128;
  unsigned short* xb  = wp; wp += (size_t)NN * HH;
  unsigned short* P_l = wp; wp += (size_t)NN * HH;
  unsigned short* Q_l = wp; wp += (size_t)NN * HH;
  unsigned short* P_m = wp; wp += (size_t)NN * HH;
  unsigned short* Q_m = wp; wp += (size_t)NN * HH;
  unsigned short* P_g = wp; wp += (size_t)NN * HH;
  unsigned short* Q_g = wp; wp += (size_t)NN * HH;
  float* fp = (float*)wp;
  float* Cf   = fp; fp += 6 * 128 * 128;   // raw combined weights (f32)
  float* cgv  = fp; fp += 3 * 128;
  float* cuv  = fp; fp += 3 * 128;
  int* ip = (int*)fp;
  int* cnt    = ip; ip += 3 * NN;
  int* offs   = ip; ip += 3 * NN;
  int* rowptr = ip; ip += 3 * NN;
  int* bsum   = ip; ip += 256;
  size_t off16 = ((size_t)((char*)ip - (char*)d_ws) + 15) & ~(size_t)15;
  float4* sed = (float4*)((char*)d_ws + off16);   // Etot packed records

  hipMemsetAsync(cnt, 0, 3 * NN * sizeof(int), stream);

  // Weight swizzles (12 jobs: 10x K=128 + 2x K=512)
  SwzJobs jobs;
  jobs.src[0] = Wa1;            jobs.dst[0] = W1a_a;
  jobs.src[1] = Wa1 + 128*128;  jobs.dst[1] = W1b_a;
  jobs.src[2] = Wb1;            jobs.dst[2] = W1a_b;
  jobs.src[3] = Wb1 + 128*128;  jobs.dst[3] = W1b_b;
  jobs.src[4] = Wc1;            jobs.dst[4] = W1a_c;
  jobs.src[5] = Wc1 + 128*128;  jobs.dst[5] = W1b_c;
  jobs.src[6] = Wu2;            jobs.dst[6] = Wu2_s;
  jobs.src[7] = Wa2;            jobs.dst[7] = W2g_l;  // scratch use (overwritten by swz6 later)
  jobs.src[8] = Wb2;            jobs.dst[8] = W2g_m;  // (unused placeholders keep grid shape)
  jobs.src[9] = Wc2;            jobs.dst[9] = W2g_g;
  jobs.src[10] = Wg;            jobs.dst[10] = Wg_s;
  jobs.src[11] = Wu1;           jobs.dst[11] = Wu1_s;
  swz_all_kernel<<<640 + 512, 256, 0, stream>>>(jobs);

  // P/Q precompute (P = x@W1a; Q = x@W1b + b1) + xb write-out
  PQJobs pq;
  pq.Wswz[0] = W1a_a; pq.bias[0] = nullptr; pq.out[0] = P_l;
  pq.Wswz[1] = W1b_a; pq.bias[1] = ba1;     pq.out[1] = Q_l;
  pq.Wswz[2] = W1a_b; pq.bias[2] = nullptr; pq.out[2] = P_m;
  pq.Wswz[3] = W1b_b; pq.bias[3] = bb1;     pq.out[3] = Q_m;
  pq.Wswz[4] = W1a_c; pq.bias[4] = nullptr; pq.out[4] = P_g;
  pq.Wswz[5] = W1b_c; pq.bias[5] = bc1;     pq.out[5] = Q_g;
  pq_kernel<<<(NN + 63) / 64, 256, 0, stream>>>(x, xb, pq);

  // Combined weights: Cf[jb] = W2_s @ {Wg|Wu1} chunk  (f32), then swizzle to bf16 B-frags
  CmbJobs cj;
  const float* w2s[3] = {Wa2, Wb2, Wc2};
  for (int s = 0; s < 3; ++s) {
    cj.Af[2*s] = w2s[s];   cj.Bswz[2*s] = Wg_s;   cj.koff[2*s] = 4*(s+1);   cj.Of[2*s] = Cf + (2*s)*16384;
    cj.Af[2*s+1] = w2s[s]; cj.Bswz[2*s+1] = Wu1_s; cj.koff[2*s+1] = 4*(s+1); cj.Of[2*s+1] = Cf + (2*s+1)*16384;
  }
  cmb_kernel<<<12, 256, 0, stream>>>(cj);

  Swz6 s6;
  s6.src[0] = Cf + 0*16384; s6.dst[0] = W2g_l;
  s6.src[1] = Cf + 1*16384; s6.dst[1] = W2u_l;
  s6.src[2] = Cf + 2*16384; s6.dst[2] = W2g_m;
  s6.src[3] = Cf + 3*16384; s6.dst[3] = W2u_m;
  s6.src[4] = Cf + 4*16384; s6.dst[4] = W2g_g;
  s6.src[5] = Cf + 5*16384; s6.dst[5] = W2u_g;
  swz6_kernel<<<384, 256, 0, stream>>>(s6);

  BiasJobs bj;
  const float* b2s[3] = {ba2, bb2, bc2};
  for (int s = 0; s < 3; ++s) {
    bj.W[2*s] = Wg;    bj.b2[2*s] = b2s[s];   bj.off[2*s] = 128*(s+1);   bj.out[2*s] = cgv + 128*s;
    bj.W[2*s+1] = Wu1; bj.b2[2*s+1] = b2s[s]; bj.off[2*s+1] = 128*(s+1); bj.out[2*s+1] = cuv + 128*s;
  }
  bias_kernel<<<6, 128, 0, stream>>>(bj);

  // Counting sort by dst (packed sed + rowptr)
  hist3_kernel<<<(Etot + 255) / 256, 256, 0, stream>>>(ei_l, ei_m, ei_g, El, Em, Eg, cnt);
  const int n3 = 3 * NN;
  const int nblkA = (n3 + 1023) / 1024;
  scanA_kernel<<<nblkA, 1024, 0, stream>>>(cnt, offs, bsum, n3);
  scanB_kernel<<<1, 256, 0, stream>>>(bsum, nblkA);
  scanC_kernel<<<nblkA, 1024, 0, stream>>>(offs, rowptr, bsum, n3);
  scatter3_kernel<<<(Etot + 255) / 256, 256, 0, stream>>>(
      ei_l, ei_m, ei_g, ea_l, ea_m, ea_g, El, Em, Eg, offs, sed);

  // Edge pass: one wave per dst, scalarized metadata, plain bf16 stores
  EParams2 ep;
  ep.s[0] = {P_l, Q_l, Wa1 + 256 * 128, hl};
  ep.s[1] = {P_m, Q_m, Wb1 + 256 * 128, hm};
  ep.s[2] = {P_g, Q_g, Wc1 + 256 * 128, hg};
  ep.sed = sed; ep.rowptr = rowptr; ep.cnt = cnt;
  edge_kernel<<<(3 * NN + 3) / 4, 256, 0, stream>>>(ep);

  // Node update (msg GEMM folded in via combined weights) + LayerNorm
  NodeParams np;
  np.x = x; np.xb = xb;
  np.h[0] = hl; np.h[1] = hm; np.h[2] = hg;
  np.cnt = cnt;
  np.BG[0] = Wg_s;  np.BG[1] = W2g_l; np.BG[2] = W2g_m; np.BG[3] = W2g_g;
  np.BU[0] = Wu1_s; np.BU[1] = W2u_l; np.BU[2] = W2u_m; np.BU[3] = W2u_g;
  np.cg = cgv; np.cu = cuv;
  np.Wu2 = Wu2_s;
  np.bg = bg; np.bu1 = bu1; np.bu2 = bu2; np.gamma = gamma; np.beta = beta;
  np.out = (float*)d_out;
  node_kernel<<<(NN + 63) / 64, 256, 0, stream>>>(np);
}

// Round 11
// 362.023 us; speedup vs baseline: 1.2194x; 1.2194x over previous
//
#include <hip/hip_runtime.h>

typedef __attribute__((ext_vector_type(8))) short bf16x8;
typedef __attribute__((ext_vector_type(8))) unsigned short ushort8;
typedef __attribute__((ext_vector_type(4))) float f32x4;

#define NN 50000
#define HH 128

static __device__ __forceinline__ unsigned short f2bf(float f) {
  unsigned u = __builtin_bit_cast(unsigned, f);
  u = u + 0x7FFFu + ((u >> 16) & 1u);
  return (unsigned short)(u >> 16);
}

static __device__ __forceinline__ float bf2f(unsigned short b) {
  return __builtin_bit_cast(float, ((unsigned)b) << 16);
}

static __device__ __forceinline__ bf16x8 bfrag(const unsigned short* __restrict__ w,
                                               int kt, int nt, int lane) {
  return *reinterpret_cast<const bf16x8*>(w + (((kt * 8 + nt) * 64 + lane) << 3));
}

// Fused weight swizzle: 10 jobs with K=128 (64 blocks each), 2 jobs with K=512 (256 blocks).
struct SwzJobs {
  const float* src[12];
  unsigned short* dst[12];
};
__global__ void swz_all_kernel(SwzJobs jobs) {
  int b = blockIdx.x;
  int job, blk;
  if (b < 640) { job = b >> 6; blk = b & 63; }
  else { b -= 640; job = 10 + (b >> 8); blk = b & 255; }
  int o = blk * 256 + threadIdx.x;
  int j = o & 7, lane = (o >> 3) & 63, nt = (o >> 9) & 7, kt = o >> 12;
  int row = kt * 32 + (lane >> 4) * 8 + j;
  int col = nt * 16 + (lane & 15);
  jobs.dst[job][o] = f2bf(jobs.src[job][row * 128 + col]);
}

// P/Q precompute: 6 GEMMs out = x @ W (+bias), bf16 row-major output; also writes xb.
struct PQJobs {
  const unsigned short* Wswz[6];
  const float* bias[6];
  unsigned short* out[6];
};
__global__ __launch_bounds__(256) void pq_kernel(const float* __restrict__ x,
                                                 unsigned short* __restrict__ xb,
                                                 PQJobs jobs) {
  __shared__ unsigned short As[64][136];
  const int t = threadIdx.x;
  const int n0 = blockIdx.x * 64;
  for (int idx = t; idx < 64 * 32; idx += 256) {
    int e = idx >> 5, c4 = (idx & 31) << 2;
    int row = n0 + e;
    float4 v = make_float4(0.f, 0.f, 0.f, 0.f);
    if (row < NN) v = *reinterpret_cast<const float4*>(x + (long)row * HH + c4);
    *reinterpret_cast<ushort4*>(&As[e][c4]) =
        make_ushort4(f2bf(v.x), f2bf(v.y), f2bf(v.z), f2bf(v.w));
  }
  __syncthreads();
  for (int idx = t; idx < 64 * 32; idx += 256) {
    int e = idx >> 5, c4 = (idx & 31) << 2;
    int row = n0 + e;
    if (row < NN)
      *reinterpret_cast<ushort4*>(xb + (long)row * HH + c4) =
          *reinterpret_cast<const ushort4*>(&As[e][c4]);
  }
  const int wave = t >> 6, lane = t & 63;
  const int lr = lane & 15, lgp = lane >> 4;
  bf16x8 afr[4];
#pragma unroll
  for (int kt = 0; kt < 4; ++kt)
    afr[kt] = *reinterpret_cast<const bf16x8*>(&As[wave * 16 + lr][kt * 32 + lgp * 8]);
#pragma unroll
  for (int jb = 0; jb < 6; ++jb) {
    f32x4 acc[8];
#pragma unroll
    for (int nt = 0; nt < 8; ++nt) acc[nt] = (f32x4){0.f, 0.f, 0.f, 0.f};
#pragma unroll
    for (int kt = 0; kt < 4; ++kt)
#pragma unroll
      for (int nt = 0; nt < 8; ++nt)
        acc[nt] = __builtin_amdgcn_mfma_f32_16x16x32_bf16(
            afr[kt], bfrag(jobs.Wswz[jb], kt, nt, lane), acc[nt], 0, 0, 0);
    const float* bi = jobs.bias[jb];
    unsigned short* O = jobs.out[jb];
#pragma unroll
    for (int nt = 0; nt < 8; ++nt) {
      int col = nt * 16 + lr;
      float bv = bi ? bi[col] : 0.f;
#pragma unroll
      for (int r = 0; r < 4; ++r) {
        int row = n0 + wave * 16 + lgp * 4 + r;
        if (row < NN) O[(long)row * HH + col] = f2bf(acc[nt][r] + bv);
      }
    }
  }
}

// ---- counting-sort by destination (two-level parallel scan) ----
__global__ void hist3_kernel(const int* __restrict__ eiL, const int* __restrict__ eiM,
                             const int* __restrict__ eiG, int El, int Em, int Eg,
                             int* __restrict__ cnt) {
  int e = blockIdx.x * 256 + threadIdx.x;
  const int* ei; int E, off;
  if (e < El) { ei = eiL; E = El; off = 0; }
  else if (e < El + Em) { e -= El; ei = eiM; E = Em; off = NN; }
  else { e -= El + Em; if (e >= Eg) return; ei = eiG; E = Eg; off = 2 * NN; }
  atomicAdd(cnt + off + ei[E + e], 1);
}

__global__ void scanA_kernel(const int* __restrict__ cnt, int* __restrict__ offs,
                             int* __restrict__ bsum, int n) {
  const int t = threadIdx.x, lane = t & 63, w = t >> 6;
  const int i = blockIdx.x * 1024 + t;
  __shared__ int wsum[16], wpre[16];
  int v = (i < n) ? cnt[i] : 0;
  int inc = v;
#pragma unroll
  for (int d = 1; d < 64; d <<= 1) {
    int o = __shfl_up(inc, d, 64);
    if (lane >= d) inc += o;
  }
  if (lane == 63) wsum[w] = inc;
  __syncthreads();
  if (t == 0) {
    int run = 0;
#pragma unroll
    for (int k = 0; k < 16; ++k) { wpre[k] = run; run += wsum[k]; }
    wsum[0] = run;
  }
  __syncthreads();
  if (i < n) offs[i] = wpre[w] + inc - v;
  if (t == 0) bsum[blockIdx.x] = wsum[0];
}

__global__ void scanB_kernel(int* __restrict__ bsum, int n) {
  const int t = threadIdx.x, lane = t & 63, w = t >> 6;
  __shared__ int wsum[4];
  int v = (t < n) ? bsum[t] : 0;
  int inc = v;
#pragma unroll
  for (int d = 1; d < 64; d <<= 1) {
    int o = __shfl_up(inc, d, 64);
    if (lane >= d) inc += o;
  }
  if (lane == 63) wsum[w] = inc;
  __syncthreads();
  int wo = 0;
  for (int k = 0; k < w; ++k) wo += wsum[k];
  if (t < n) bsum[t] = wo + inc - v;
}

__global__ void scanC_kernel(int* __restrict__ offs, int* __restrict__ rowptr,
                             const int* __restrict__ bsum, int n) {
  int i = blockIdx.x * 1024 + threadIdx.x;
  if (i < n) {
    int v = offs[i] + bsum[blockIdx.x];
    offs[i] = v;
    rowptr[i] = v;
  }
}

// Scatter: packed 16B record {src_bits, ea0, ea1, ea2} at dst-sorted position.
__global__ void scatter3_kernel(const int* __restrict__ eiL, const int* __restrict__ eiM,
                                const int* __restrict__ eiG,
                                const float* __restrict__ eaL, const float* __restrict__ eaM,
                                const float* __restrict__ eaG,
                                int El, int Em, int Eg, int* __restrict__ offs,
                                float4* __restrict__ sed) {
  int e = blockIdx.x * 256 + threadIdx.x;
  const int* ei; const float* ea; int E, off;
  if (e < El) { ei = eiL; ea = eaL; E = El; off = 0; }
  else if (e < El + Em) { e -= El; ei = eiM; ea = eaM; E = Em; off = NN; }
  else { e -= El + Em; if (e >= Eg) return; ei = eiG; ea = eaG; E = Eg; off = 2 * NN; }
  int d = ei[E + e];
  int p = atomicAdd(offs + off + d, 1);
  sed[p] = make_float4(__int_as_float(ei[e]),
                       ea[(long)e * 3 + 0], ea[(long)e * 3 + 1], ea[(long)e * 3 + 2]);
}

// ---- edge kernel: one WAVE per dst (CSR run), scalarized metadata.
// hagg[dst] = bf16(sum relu(P[src]+Q[dst]+ea.Wc)). Plain stores, no atomics/LDS/barriers.
struct EScale2 { const unsigned short *P, *Q; const float* Wc; unsigned short* hag; };
struct EParams2 {
  EScale2 s[3];
  const float4* sed;
  const int* rowptr; const int* cnt;
};
__global__ __launch_bounds__(256) void edge_kernel(EParams2 prm) {
  const int t = threadIdx.x;
  const int wave = t >> 6, lane = t & 63;
  int gidv = blockIdx.x * 4 + wave;
  if (gidv >= 3 * NN) return;
  const int gid = __builtin_amdgcn_readfirstlane(gidv);
  const int si = (gid >= NN) + (gid >= 2 * NN);
  const int dst = gid - si * NN;
  const EScale2 S = prm.s[si];
  const int base = __builtin_amdgcn_readfirstlane(prm.rowptr[gid]);
  const int len = __builtin_amdgcn_readfirstlane(prm.cnt[gid]);
  const int c2 = lane * 2;

  const float wcA0 = S.Wc[c2],       wcB0 = S.Wc[c2 + 1];
  const float wcA1 = S.Wc[128 + c2], wcB1 = S.Wc[129 + c2];
  const float wcA2 = S.Wc[256 + c2], wcB2 = S.Wc[257 + c2];

  float aA0 = 0.f, aB0 = 0.f, aA1 = 0.f, aB1 = 0.f;
  if (len > 0) {
    ushort2 qv = *reinterpret_cast<const ushort2*>(S.Q + (long)dst * HH + c2);
    const float qA = bf2f(qv.x), qB = bf2f(qv.y);
    const float4* __restrict__ ep = prm.sed + base;
    int i = 0;
    for (; i + 4 <= len; i += 4) {
      float4 m0 = ep[i], m1 = ep[i + 1], m2 = ep[i + 2], m3 = ep[i + 3];
      ushort2 p0 = *reinterpret_cast<const ushort2*>(S.P + (long)__float_as_int(m0.x) * HH + c2);
      ushort2 p1 = *reinterpret_cast<const ushort2*>(S.P + (long)__float_as_int(m1.x) * HH + c2);
      ushort2 p2 = *reinterpret_cast<const ushort2*>(S.P + (long)__float_as_int(m2.x) * HH + c2);
      ushort2 p3 = *reinterpret_cast<const ushort2*>(S.P + (long)__float_as_int(m3.x) * HH + c2);
      aA0 += fmaxf(bf2f(p0.x) + qA + m0.y * wcA0 + m0.z * wcA1 + m0.w * wcA2, 0.f);
      aB0 += fmaxf(bf2f(p0.y) + qB + m0.y * wcB0 + m0.z * wcB1 + m0.w * wcB2, 0.f);
      aA1 += fmaxf(bf2f(p1.x) + qA + m1.y * wcA0 + m1.z * wcA1 + m1.w * wcA2, 0.f);
      aB1 += fmaxf(bf2f(p1.y) + qB + m1.y * wcB0 + m1.z * wcB1 + m1.w * wcB2, 0.f);
      aA0 += fmaxf(bf2f(p2.x) + qA + m2.y * wcA0 + m2.z * wcA1 + m2.w * wcA2, 0.f);
      aB0 += fmaxf(bf2f(p2.y) + qB + m2.y * wcB0 + m2.z * wcB1 + m2.w * wcB2, 0.f);
      aA1 += fmaxf(bf2f(p3.x) + qA + m3.y * wcA0 + m3.z * wcA1 + m3.w * wcA2, 0.f);
      aB1 += fmaxf(bf2f(p3.y) + qB + m3.y * wcB0 + m3.z * wcB1 + m3.w * wcB2, 0.f);
    }
    for (; i < len; ++i) {
      float4 m0 = ep[i];
      ushort2 p0 = *reinterpret_cast<const ushort2*>(S.P + (long)__float_as_int(m0.x) * HH + c2);
      aA0 += fmaxf(bf2f(p0.x) + qA + m0.y * wcA0 + m0.z * wcA1 + m0.w * wcA2, 0.f);
      aB0 += fmaxf(bf2f(p0.y) + qB + m0.y * wcB0 + m0.z * wcB1 + m0.w * wcB2, 0.f);
    }
  }
  *reinterpret_cast<ushort2*>(S.hag + (long)dst * HH + c2) =
      make_ushort2(f2bf(aA0 + aA1), f2bf(aB0 + aB1));
}

// ---- msg kernel: M_s = bf16(hagg_s @ W2_s + deg_s*b2_s); A-frags straight from bf16 hagg ----
struct MsgScale {
  const unsigned short* H; const unsigned short* W2s; const float* b2; const int* deg;
  unsigned short* M;
};
struct MsgParams { MsgScale s[3]; };
__global__ __launch_bounds__(256) void msg_kernel(MsgParams prm) {
  const int bid = blockIdx.x;
  const int si = bid % 3;
  const int n0 = (bid / 3) * 64;
  const MsgScale S = prm.s[si];
  const int t = threadIdx.x;
  const int wave = t >> 6, lane = t & 63;
  const int lr = lane & 15, lgp = lane >> 4;
  const int arow = n0 + wave * 16 + lr;
  const bool aok = arow < NN;
  f32x4 acc[8];
#pragma unroll
  for (int nt = 0; nt < 8; ++nt) acc[nt] = (f32x4){0.f, 0.f, 0.f, 0.f};
#pragma unroll
  for (int kt = 0; kt < 4; ++kt) {
    bf16x8 a = (bf16x8){0, 0, 0, 0, 0, 0, 0, 0};
    if (aok)
      a = *reinterpret_cast<const bf16x8*>(S.H + (long)arow * HH + kt * 32 + lgp * 8);
#pragma unroll
    for (int nt = 0; nt < 8; ++nt)
      acc[nt] = __builtin_amdgcn_mfma_f32_16x16x32_bf16(
          a, bfrag(S.W2s, kt, nt, lane), acc[nt], 0, 0, 0);
  }
#pragma unroll
  for (int nt = 0; nt < 8; ++nt) {
    int col = nt * 16 + lr;
    float bv = S.b2[col];
#pragma unroll
    for (int r = 0; r < 4; ++r) {
      int row = n0 + wave * 16 + lgp * 4 + r;
      if (row < NN) {
        float dg = (float)S.deg[row];
        S.M[(long)row * HH + col] = f2bf(acc[nt][r] + dg * bv);
      }
    }
  }
}

// ---- node kernel: streaming K=512 over bf16 [xb|Ml|Mm|Mg], two GEMMs + Wu2 + LN ----
__global__ __launch_bounds__(256) void node_kernel(
    const float* __restrict__ x, const unsigned short* __restrict__ xb,
    const unsigned short* __restrict__ Ml, const unsigned short* __restrict__ Mm,
    const unsigned short* __restrict__ Mg,
    const unsigned short* __restrict__ Wg, const unsigned short* __restrict__ Wu1,
    const unsigned short* __restrict__ Wu2,
    const float* __restrict__ bg, const float* __restrict__ bu1, const float* __restrict__ bu2,
    const float* __restrict__ gamma, const float* __restrict__ beta,
    float* __restrict__ out) {
  __shared__ unsigned short Hs[64][136];
  const int t = threadIdx.x;
  const int n0 = blockIdx.x * 64;
  const int wave = t >> 6, lane = t & 63;
  const int lr = lane & 15, lgp = lane >> 4;

  f32x4 accG[8], accH[8];
#pragma unroll
  for (int nt = 0; nt < 8; ++nt) {
    accG[nt] = (f32x4){0.f, 0.f, 0.f, 0.f};
    accH[nt] = (f32x4){0.f, 0.f, 0.f, 0.f};
  }
  const int arow = n0 + wave * 16 + lr;
  const bool aok = arow < NN;

#pragma unroll
  for (int kt = 0; kt < 16; ++kt) {
    const unsigned short* S = (kt < 4) ? xb : (kt < 8) ? Ml : (kt < 12) ? Mm : Mg;
    int cb = ((kt & 3) << 5) + (lgp << 3);
    bf16x8 a = (bf16x8){0, 0, 0, 0, 0, 0, 0, 0};
    if (aok) a = *reinterpret_cast<const bf16x8*>(S + (long)arow * HH + cb);
#pragma unroll
    for (int nt = 0; nt < 8; ++nt) {
      accG[nt] = __builtin_amdgcn_mfma_f32_16x16x32_bf16(a, bfrag(Wg, kt, nt, lane), accG[nt], 0, 0, 0);
      accH[nt] = __builtin_amdgcn_mfma_f32_16x16x32_bf16(a, bfrag(Wu1, kt, nt, lane), accH[nt], 0, 0, 0);
    }
  }

#pragma unroll
  for (int nt = 0; nt < 8; ++nt) {
    int col = nt * 16 + lr;
    float bgv = bg[col], bhv = bu1[col];
#pragma unroll
    for (int r = 0; r < 4; ++r) {
      float g = 1.f / (1.f + __expf(-(accG[nt][r] + bgv)));
      accG[nt][r] = g;
      float h = fmaxf(accH[nt][r] + bhv, 0.f);
      Hs[wave * 16 + lgp * 4 + r][col] = f2bf(h);
    }
  }

  f32x4 accU[8];
#pragma unroll
  for (int nt = 0; nt < 8; ++nt) accU[nt] = (f32x4){0.f, 0.f, 0.f, 0.f};
#pragma unroll
  for (int kt = 0; kt < 4; ++kt) {
    bf16x8 a = *reinterpret_cast<const bf16x8*>(&Hs[wave * 16 + lr][kt * 32 + lgp * 8]);
#pragma unroll
    for (int nt = 0; nt < 8; ++nt) {
      accU[nt] = __builtin_amdgcn_mfma_f32_16x16x32_bf16(a, bfrag(Wu2, kt, nt, lane), accU[nt], 0, 0, 0);
    }
  }

#pragma unroll
  for (int nt = 0; nt < 8; ++nt) {
    int col = nt * 16 + lr;
    float b2v = bu2[col];
#pragma unroll
    for (int r = 0; r < 4; ++r) {
      int row = n0 + wave * 16 + lgp * 4 + r;
      float xv = (row < NN) ? x[(long)row * HH + col] : 0.f;
      float u = accU[nt][r] + b2v;
      float g = accG[nt][r];
      accU[nt][r] = g * u + (1.f - g) * xv;
    }
  }

#pragma unroll
  for (int r = 0; r < 4; ++r) {
    int row = n0 + wave * 16 + lgp * 4 + r;
    float s = 0.f;
#pragma unroll
    for (int nt = 0; nt < 8; ++nt) s += accU[nt][r];
    s += __shfl_xor(s, 1, 64);
    s += __shfl_xor(s, 2, 64);
    s += __shfl_xor(s, 4, 64);
    s += __shfl_xor(s, 8, 64);
    float mu = s * (1.f / 128.f);
    float qv = 0.f;
#pragma unroll
    for (int nt = 0; nt < 8; ++nt) {
      float d = accU[nt][r] - mu;
      qv += d * d;
    }
    qv += __shfl_xor(qv, 1, 64);
    qv += __shfl_xor(qv, 2, 64);
    qv += __shfl_xor(qv, 4, 64);
    qv += __shfl_xor(qv, 8, 64);
    float rs = rsqrtf(qv * (1.f / 128.f) + 1e-5f);
    if (row < NN) {
#pragma unroll
      for (int nt = 0; nt < 8; ++nt) {
        int col = nt * 16 + lr;
        out[(long)row * HH + col] = (accU[nt][r] - mu) * rs * gamma[col] + beta[col];
      }
    }
  }
}

extern "C" void kernel_launch(void* const* d_in, const int* in_sizes, int n_in,
                              void* d_out, int out_size, void* d_ws, size_t ws_size,
                              hipStream_t stream) {
  const float* x = (const float*)d_in[0];
  const int* ei_l = (const int*)d_in[1];
  const float* ea_l = (const float*)d_in[2];
  const int* ei_m = (const int*)d_in[3];
  const float* ea_m = (const float*)d_in[4];
  const int* ei_g = (const int*)d_in[5];
  const float* ea_g = (const float*)d_in[6];
  const float* Wa1 = (const float*)d_in[7];
  const float* ba1 = (const float*)d_in[8];
  const float* Wa2 = (const float*)d_in[9];
  const float* ba2 = (const float*)d_in[10];
  const float* Wb1 = (const float*)d_in[11];
  const float* bb1 = (const float*)d_in[12];
  const float* Wb2 = (const float*)d_in[13];
  const float* bb2 = (const float*)d_in[14];
  const float* Wc1 = (const float*)d_in[15];
  const float* bc1 = (const float*)d_in[16];
  const float* Wc2 = (const float*)d_in[17];
  const float* bc2 = (const float*)d_in[18];
  const float* Wg = (const float*)d_in[19];
  const float* bg = (const float*)d_in[20];
  const float* Wu1 = (const float*)d_in[21];
  const float* bu1 = (const float*)d_in[22];
  const float* Wu2 = (const float*)d_in[23];
  const float* bu2 = (const float*)d_in[24];
  const float* gamma = (const float*)d_in[25];
  const float* beta = (const float*)d_in[26];

  const int El = in_sizes[1] / 2;
  const int Em = in_sizes[3] / 2;
  const int Eg = in_sizes[5] / 2;
  const int Etot = El + Em + Eg;

  // Workspace layout (hagg bf16)
  unsigned short* wp = (unsigned short*)d_ws;
  unsigned short* hl = wp; wp += (size_t)NN * HH;
  unsigned short* hm = wp; wp += (size_t)NN * HH;
  unsigned short* hg = wp; wp += (size_t)NN * HH;
  unsigned short* W1a_a = wp; wp += 128 * 128;
  unsigned short* W1b_a = wp; wp += 128 * 128;
  unsigned short* W2_a  = wp; wp += 128 * 128;
  unsigned short* W1a_b = wp; wp += 128 * 128;
  unsigned short* W1b_b = wp; wp += 128 * 128;
  unsigned short* W2_b  = wp; wp += 128 * 128;
  unsigned short* W1a_c = wp; wp += 128 * 128;
  unsigned short* W1b_c = wp; wp += 128 * 128;
  unsigned short* W2_c  = wp; wp += 128 * 128;
  unsigned short* Wu2_s = wp; wp += 128 * 128;
  unsigned short* Wg_s  = wp; wp += 512 * 128;
  unsigned short* Wu1_s = wp; wp += 512 * 128;
  unsigned short* xb  = wp; wp += (size_t)NN * HH;
  unsigned short* P_l = wp; wp += (size_t)NN * HH;
  unsigned short* Q_l = wp; wp += (size_t)NN * HH;
  unsigned short* P_m = wp; wp += (size_t)NN * HH;
  unsigned short* Q_m = wp; wp += (size_t)NN * HH;
  unsigned short* P_g = wp; wp += (size_t)NN * HH;
  unsigned short* Q_g = wp; wp += (size_t)NN * HH;
  unsigned short* M_l = P_l;   // alias (P dead after edge_kernel)
  unsigned short* M_m = P_m;
  unsigned short* M_g = P_g;
  int* ip = (int*)wp;
  int* cnt    = ip; ip += 3 * NN;   // degrees (kept)
  int* offs   = ip; ip += 3 * NN;   // consumed by scatter
  int* rowptr = ip; ip += 3 * NN;   // kept for edge kernel
  int* bsum   = ip; ip += 256;
  size_t off16 = ((size_t)((char*)ip - (char*)d_ws) + 15) & ~(size_t)15;
  float4* sed = (float4*)((char*)d_ws + off16);   // Etot packed records

  hipMemsetAsync(cnt, 0, 3 * NN * sizeof(int), stream);

  // Weight swizzles
  SwzJobs jobs;
  jobs.src[0] = Wa1;            jobs.dst[0] = W1a_a;
  jobs.src[1] = Wa1 + 128*128;  jobs.dst[1] = W1b_a;
  jobs.src[2] = Wa2;            jobs.dst[2] = W2_a;
  jobs.src[3] = Wb1;            jobs.dst[3] = W1a_b;
  jobs.src[4] = Wb1 + 128*128;  jobs.dst[4] = W1b_b;
  jobs.src[5] = Wb2;            jobs.dst[5] = W2_b;
  jobs.src[6] = Wc1;            jobs.dst[6] = W1a_c;
  jobs.src[7] = Wc1 + 128*128;  jobs.dst[7] = W1b_c;
  jobs.src[8] = Wc2;            jobs.dst[8] = W2_c;
  jobs.src[9] = Wu2;            jobs.dst[9] = Wu2_s;
  jobs.src[10] = Wg;            jobs.dst[10] = Wg_s;
  jobs.src[11] = Wu1;           jobs.dst[11] = Wu1_s;
  swz_all_kernel<<<640 + 512, 256, 0, stream>>>(jobs);

  // P/Q precompute (P = x@W1a; Q = x@W1b + b1) + xb write-out
  PQJobs pq;
  pq.Wswz[0] = W1a_a; pq.bias[0] = nullptr; pq.out[0] = P_l;
  pq.Wswz[1] = W1b_a; pq.bias[1] = ba1;     pq.out[1] = Q_l;
  pq.Wswz[2] = W1a_b; pq.bias[2] = nullptr; pq.out[2] = P_m;
  pq.Wswz[3] = W1b_b; pq.bias[3] = bb1;     pq.out[3] = Q_m;
  pq.Wswz[4] = W1a_c; pq.bias[4] = nullptr; pq.out[4] = P_g;
  pq.Wswz[5] = W1b_c; pq.bias[5] = bc1;     pq.out[5] = Q_g;
  pq_kernel<<<(NN + 63) / 64, 256, 0, stream>>>(x, xb, pq);

  // Counting sort by dst (packed sed + rowptr)
  hist3_kernel<<<(Etot + 255) / 256, 256, 0, stream>>>(ei_l, ei_m, ei_g, El, Em, Eg, cnt);
  const int n3 = 3 * NN;
  const int nblkA = (n3 + 1023) / 1024;
  scanA_kernel<<<nblkA, 1024, 0, stream>>>(cnt, offs, bsum, n3);
  scanB_kernel<<<1, 256, 0, stream>>>(bsum, nblkA);
  scanC_kernel<<<nblkA, 1024, 0, stream>>>(offs, rowptr, bsum, n3);
  scatter3_kernel<<<(Etot + 255) / 256, 256, 0, stream>>>(
      ei_l, ei_m, ei_g, ea_l, ea_m, ea_g, El, Em, Eg, offs, sed);

  // Edge pass: one wave per dst, scalarized metadata, plain bf16 stores
  EParams2 ep;
  ep.s[0] = {P_l, Q_l, Wa1 + 256 * 128, hl};
  ep.s[1] = {P_m, Q_m, Wb1 + 256 * 128, hm};
  ep.s[2] = {P_g, Q_g, Wc1 + 256 * 128, hg};
  ep.sed = sed; ep.rowptr = rowptr; ep.cnt = cnt;
  edge_kernel<<<(3 * NN + 3) / 4, 256, 0, stream>>>(ep);

  // Msg pass: M_s = bf16(hagg_s @ W2_s + deg*b2_s)
  MsgParams mp;
  mp.s[0] = {hl, W2_a, ba2, cnt,          M_l};
  mp.s[1] = {hm, W2_b, bb2, cnt + NN,     M_m};
  mp.s[2] = {hg, W2_c, bc2, cnt + 2 * NN, M_g};
  const int NB = (NN + 63) / 64;
  msg_kernel<<<3 * NB, 256, 0, stream>>>(mp);

  // Node update + LayerNorm (all-bf16 A-stream)
  node_kernel<<<NB, 256, 0, stream>>>(x, xb, M_l, M_m, M_g, Wg_s, Wu1_s, Wu2_s,
                                      bg, bu1, bu2, gamma, beta, (float*)d_out);
}

// Round 12
// 341.200 us; speedup vs baseline: 1.2938x; 1.0610x over previous
//
#include <hip/hip_runtime.h>

typedef __attribute__((ext_vector_type(8))) short bf16x8;
typedef __attribute__((ext_vector_type(8))) unsigned short ushort8;
typedef __attribute__((ext_vector_type(4))) float f32x4;

#define NN 50000
#define HH 128

static __device__ __forceinline__ unsigned short f2bf(float f) {
  unsigned u = __builtin_bit_cast(unsigned, f);
  u = u + 0x7FFFu + ((u >> 16) & 1u);
  return (unsigned short)(u >> 16);
}

static __device__ __forceinline__ float bf2f(unsigned short b) {
  return __builtin_bit_cast(float, ((unsigned)b) << 16);
}

static __device__ __forceinline__ bf16x8 bfrag(const unsigned short* __restrict__ w,
                                               int kt, int nt, int lane) {
  return *reinterpret_cast<const bf16x8*>(w + (((kt * 8 + nt) * 64 + lane) << 3));
}

// Fused weight swizzle: 10 jobs with K=128 (64 blocks each), 2 jobs with K=512 (256 blocks).
struct SwzJobs {
  const float* src[12];
  unsigned short* dst[12];
};
__global__ void swz_all_kernel(SwzJobs jobs) {
  int b = blockIdx.x;
  int job, blk;
  if (b < 640) { job = b >> 6; blk = b & 63; }
  else { b -= 640; job = 10 + (b >> 8); blk = b & 255; }
  int o = blk * 256 + threadIdx.x;
  int j = o & 7, lane = (o >> 3) & 63, nt = (o >> 9) & 7, kt = o >> 12;
  int row = kt * 32 + (lane >> 4) * 8 + j;
  int col = nt * 16 + (lane & 15);
  jobs.dst[job][o] = f2bf(jobs.src[job][row * 128 + col]);
}

// P/Q precompute: 6 GEMMs out = x @ W (+bias), bf16 row-major; jb split across blocks.
// xb (bf16 copy of x) written by jb==0 blocks.
struct PQJobs {
  const unsigned short* Wswz[6];
  const float* bias[6];
  unsigned short* out[6];
};
__global__ __launch_bounds__(256) void pq_kernel(const float* __restrict__ x,
                                                 unsigned short* __restrict__ xb,
                                                 PQJobs jobs) {
  __shared__ unsigned short As[64][136];
  const int t = threadIdx.x;
  const int bid = blockIdx.x;
  const int jb = bid % 6;
  const int n0 = (bid / 6) * 64;
  for (int idx = t; idx < 64 * 32; idx += 256) {
    int e = idx >> 5, c4 = (idx & 31) << 2;
    int row = n0 + e;
    float4 v = make_float4(0.f, 0.f, 0.f, 0.f);
    if (row < NN) v = *reinterpret_cast<const float4*>(x + (long)row * HH + c4);
    *reinterpret_cast<ushort4*>(&As[e][c4]) =
        make_ushort4(f2bf(v.x), f2bf(v.y), f2bf(v.z), f2bf(v.w));
  }
  __syncthreads();
  if (jb == 0) {
    for (int idx = t; idx < 64 * 32; idx += 256) {
      int e = idx >> 5, c4 = (idx & 31) << 2;
      int row = n0 + e;
      if (row < NN)
        *reinterpret_cast<ushort4*>(xb + (long)row * HH + c4) =
            *reinterpret_cast<const ushort4*>(&As[e][c4]);
    }
  }
  const int wave = t >> 6, lane = t & 63;
  const int lr = lane & 15, lgp = lane >> 4;
  bf16x8 afr[4];
#pragma unroll
  for (int kt = 0; kt < 4; ++kt)
    afr[kt] = *reinterpret_cast<const bf16x8*>(&As[wave * 16 + lr][kt * 32 + lgp * 8]);
  f32x4 acc[8];
#pragma unroll
  for (int nt = 0; nt < 8; ++nt) acc[nt] = (f32x4){0.f, 0.f, 0.f, 0.f};
  const unsigned short* W = jobs.Wswz[jb];
#pragma unroll
  for (int kt = 0; kt < 4; ++kt)
#pragma unroll
    for (int nt = 0; nt < 8; ++nt)
      acc[nt] = __builtin_amdgcn_mfma_f32_16x16x32_bf16(
          afr[kt], bfrag(W, kt, nt, lane), acc[nt], 0, 0, 0);
  const float* bi = jobs.bias[jb];
  unsigned short* O = jobs.out[jb];
#pragma unroll
  for (int nt = 0; nt < 8; ++nt) {
    int col = nt * 16 + lr;
    float bv = bi ? bi[col] : 0.f;
#pragma unroll
    for (int r = 0; r < 4; ++r) {
      int row = n0 + wave * 16 + lgp * 4 + r;
      if (row < NN) O[(long)row * HH + col] = f2bf(acc[nt][r] + bv);
    }
  }
}

// ---- counting-sort by destination (two-level parallel scan) ----
__global__ void hist3_kernel(const int* __restrict__ eiL, const int* __restrict__ eiM,
                             const int* __restrict__ eiG, int El, int Em, int Eg,
                             int* __restrict__ cnt) {
  int e = blockIdx.x * 256 + threadIdx.x;
  const int* ei; int E, off;
  if (e < El) { ei = eiL; E = El; off = 0; }
  else if (e < El + Em) { e -= El; ei = eiM; E = Em; off = NN; }
  else { e -= El + Em; if (e >= Eg) return; ei = eiG; E = Eg; off = 2 * NN; }
  atomicAdd(cnt + off + ei[E + e], 1);
}

__global__ void scanA_kernel(const int* __restrict__ cnt, int* __restrict__ offs,
                             int* __restrict__ bsum, int n) {
  const int t = threadIdx.x, lane = t & 63, w = t >> 6;
  const int i = blockIdx.x * 1024 + t;
  __shared__ int wsum[16], wpre[16];
  int v = (i < n) ? cnt[i] : 0;
  int inc = v;
#pragma unroll
  for (int d = 1; d < 64; d <<= 1) {
    int o = __shfl_up(inc, d, 64);
    if (lane >= d) inc += o;
  }
  if (lane == 63) wsum[w] = inc;
  __syncthreads();
  if (t == 0) {
    int run = 0;
#pragma unroll
    for (int k = 0; k < 16; ++k) { wpre[k] = run; run += wsum[k]; }
    wsum[0] = run;
  }
  __syncthreads();
  if (i < n) offs[i] = wpre[w] + inc - v;
  if (t == 0) bsum[blockIdx.x] = wsum[0];
}

__global__ void scanB_kernel(int* __restrict__ bsum, int n) {
  const int t = threadIdx.x, lane = t & 63, w = t >> 6;
  __shared__ int wsum[4];
  int v = (t < n) ? bsum[t] : 0;
  int inc = v;
#pragma unroll
  for (int d = 1; d < 64; d <<= 1) {
    int o = __shfl_up(inc, d, 64);
    if (lane >= d) inc += o;
  }
  if (lane == 63) wsum[w] = inc;
  __syncthreads();
  int wo = 0;
  for (int k = 0; k < w; ++k) wo += wsum[k];
  if (t < n) bsum[t] = wo + inc - v;
}

__global__ void scanC_kernel(int* __restrict__ offs, int* __restrict__ rowptr,
                             const int* __restrict__ bsum, int n) {
  int i = blockIdx.x * 1024 + threadIdx.x;
  if (i < n) {
    int v = offs[i] + bsum[blockIdx.x];
    offs[i] = v;
    rowptr[i] = v;
  }
}

// Scatter: packed 16B record {src_bits, ea0, ea1, ea2} at dst-sorted position.
__global__ void scatter3_kernel(const int* __restrict__ eiL, const int* __restrict__ eiM,
                                const int* __restrict__ eiG,
                                const float* __restrict__ eaL, const float* __restrict__ eaM,
                                const float* __restrict__ eaG,
                                int El, int Em, int Eg, int* __restrict__ offs,
                                float4* __restrict__ sed) {
  int e = blockIdx.x * 256 + threadIdx.x;
  const int* ei; const float* ea; int E, off;
  if (e < El) { ei = eiL; ea = eaL; E = El; off = 0; }
  else if (e < El + Em) { e -= El; ei = eiM; ea = eaM; E = Em; off = NN; }
  else { e -= El + Em; if (e >= Eg) return; ei = eiG; ea = eaG; E = Eg; off = 2 * NN; }
  int d = ei[E + e];
  int p = atomicAdd(offs + off + d, 1);
  sed[p] = make_float4(__int_as_float(ei[e]),
                       ea[(long)e * 3 + 0], ea[(long)e * 3 + 1], ea[(long)e * 3 + 2]);
}

// ---- edge kernel: one WAVE per dst (CSR run), scalarized metadata.
struct EScale2 { const unsigned short *P, *Q; const float* Wc; unsigned short* hag; };
struct EParams2 {
  EScale2 s[3];
  const float4* sed;
  const int* rowptr; const int* cnt;
};
__global__ __launch_bounds__(256) void edge_kernel(EParams2 prm) {
  const int t = threadIdx.x;
  const int wave = t >> 6, lane = t & 63;
  int gidv = blockIdx.x * 4 + wave;
  if (gidv >= 3 * NN) return;
  const int gid = __builtin_amdgcn_readfirstlane(gidv);
  const int si = (gid >= NN) + (gid >= 2 * NN);
  const int dst = gid - si * NN;
  const EScale2 S = prm.s[si];
  const int base = __builtin_amdgcn_readfirstlane(prm.rowptr[gid]);
  const int len = __builtin_amdgcn_readfirstlane(prm.cnt[gid]);
  const int c2 = lane * 2;

  const float wcA0 = S.Wc[c2],       wcB0 = S.Wc[c2 + 1];
  const float wcA1 = S.Wc[128 + c2], wcB1 = S.Wc[129 + c2];
  const float wcA2 = S.Wc[256 + c2], wcB2 = S.Wc[257 + c2];

  float aA0 = 0.f, aB0 = 0.f, aA1 = 0.f, aB1 = 0.f;
  if (len > 0) {
    ushort2 qv = *reinterpret_cast<const ushort2*>(S.Q + (long)dst * HH + c2);
    const float qA = bf2f(qv.x), qB = bf2f(qv.y);
    const float4* __restrict__ ep = prm.sed + base;
    int i = 0;
    for (; i + 4 <= len; i += 4) {
      float4 m0 = ep[i], m1 = ep[i + 1], m2 = ep[i + 2], m3 = ep[i + 3];
      ushort2 p0 = *reinterpret_cast<const ushort2*>(S.P + (long)__float_as_int(m0.x) * HH + c2);
      ushort2 p1 = *reinterpret_cast<const ushort2*>(S.P + (long)__float_as_int(m1.x) * HH + c2);
      ushort2 p2 = *reinterpret_cast<const ushort2*>(S.P + (long)__float_as_int(m2.x) * HH + c2);
      ushort2 p3 = *reinterpret_cast<const ushort2*>(S.P + (long)__float_as_int(m3.x) * HH + c2);
      aA0 += fmaxf(bf2f(p0.x) + qA + m0.y * wcA0 + m0.z * wcA1 + m0.w * wcA2, 0.f);
      aB0 += fmaxf(bf2f(p0.y) + qB + m0.y * wcB0 + m0.z * wcB1 + m0.w * wcB2, 0.f);
      aA1 += fmaxf(bf2f(p1.x) + qA + m1.y * wcA0 + m1.z * wcA1 + m1.w * wcA2, 0.f);
      aB1 += fmaxf(bf2f(p1.y) + qB + m1.y * wcB0 + m1.z * wcB1 + m1.w * wcB2, 0.f);
      aA0 += fmaxf(bf2f(p2.x) + qA + m2.y * wcA0 + m2.z * wcA1 + m2.w * wcA2, 0.f);
      aB0 += fmaxf(bf2f(p2.y) + qB + m2.y * wcB0 + m2.z * wcB1 + m2.w * wcB2, 0.f);
      aA1 += fmaxf(bf2f(p3.x) + qA + m3.y * wcA0 + m3.z * wcA1 + m3.w * wcA2, 0.f);
      aB1 += fmaxf(bf2f(p3.y) + qB + m3.y * wcB0 + m3.z * wcB1 + m3.w * wcB2, 0.f);
    }
    for (; i < len; ++i) {
      float4 m0 = ep[i];
      ushort2 p0 = *reinterpret_cast<const ushort2*>(S.P + (long)__float_as_int(m0.x) * HH + c2);
      aA0 += fmaxf(bf2f(p0.x) + qA + m0.y * wcA0 + m0.z * wcA1 + m0.w * wcA2, 0.f);
      aB0 += fmaxf(bf2f(p0.y) + qB + m0.y * wcB0 + m0.z * wcB1 + m0.w * wcB2, 0.f);
    }
  }
  *reinterpret_cast<ushort2*>(S.hag + (long)dst * HH + c2) =
      make_ushort2(f2bf(aA0 + aA1), f2bf(aB0 + aB1));
}

// ---- msg kernel: M_s = bf16(hagg_s @ W2_s + deg_s*b2_s) ----
struct MsgScale {
  const unsigned short* H; const unsigned short* W2s; const float* b2; const int* deg;
  unsigned short* M;
};
struct MsgParams { MsgScale s[3]; };
__global__ __launch_bounds__(256) void msg_kernel(MsgParams prm) {
  const int bid = blockIdx.x;
  const int si = bid % 3;
  const int n0 = (bid / 3) * 64;
  const MsgScale S = prm.s[si];
  const int t = threadIdx.x;
  const int wave = t >> 6, lane = t & 63;
  const int lr = lane & 15, lgp = lane >> 4;
  const int arow = n0 + wave * 16 + lr;
  const bool aok = arow < NN;
  f32x4 acc[8];
#pragma unroll
  for (int nt = 0; nt < 8; ++nt) acc[nt] = (f32x4){0.f, 0.f, 0.f, 0.f};
#pragma unroll
  for (int kt = 0; kt < 4; ++kt) {
    bf16x8 a = (bf16x8){0, 0, 0, 0, 0, 0, 0, 0};
    if (aok)
      a = *reinterpret_cast<const bf16x8*>(S.H + (long)arow * HH + kt * 32 + lgp * 8);
#pragma unroll
    for (int nt = 0; nt < 8; ++nt)
      acc[nt] = __builtin_amdgcn_mfma_f32_16x16x32_bf16(
          a, bfrag(S.W2s, kt, nt, lane), acc[nt], 0, 0, 0);
  }
#pragma unroll
  for (int nt = 0; nt < 8; ++nt) {
    int col = nt * 16 + lr;
    float bv = S.b2[col];
#pragma unroll
    for (int r = 0; r < 4; ++r) {
      int row = n0 + wave * 16 + lgp * 4 + r;
      if (row < NN) {
        float dg = (float)S.deg[row];
        S.M[(long)row * HH + col] = f2bf(acc[nt][r] + dg * bv);
      }
    }
  }
}

// ---- node kernel: K=512 streaming GEMM with double-buffered LDS B-staging ----
// smem[2][8192]: per kt, G frags at [0..4095], U frags at [4096..8191] (shorts).
__global__ __launch_bounds__(256) void node_kernel(
    const float* __restrict__ x, const unsigned short* __restrict__ xb,
    const unsigned short* __restrict__ Ml, const unsigned short* __restrict__ Mm,
    const unsigned short* __restrict__ Mg,
    const unsigned short* __restrict__ Wg, const unsigned short* __restrict__ Wu1,
    const unsigned short* __restrict__ Wu2,
    const float* __restrict__ bg, const float* __restrict__ bu1, const float* __restrict__ bu2,
    const float* __restrict__ gamma, const float* __restrict__ beta,
    float* __restrict__ out) {
  __shared__ unsigned short smem[2][8192];
  const int t = threadIdx.x;
  const int n0 = blockIdx.x * 64;
  const int wave = t >> 6, lane = t & 63;
  const int lr = lane & 15, lgp = lane >> 4;
  const int arow = n0 + wave * 16 + lr;
  const bool aok = arow < NN;

  f32x4 accG[8], accH[8];
#pragma unroll
  for (int nt = 0; nt < 8; ++nt) {
    accG[nt] = (f32x4){0.f, 0.f, 0.f, 0.f};
    accH[nt] = (f32x4){0.f, 0.f, 0.f, 0.f};
  }

  // prologue: stage kt=0 into buf 0
  {
    ushort8 g0 = *reinterpret_cast<const ushort8*>(Wg + t * 8);
    ushort8 g1 = *reinterpret_cast<const ushort8*>(Wg + 2048 + t * 8);
    ushort8 u0 = *reinterpret_cast<const ushort8*>(Wu1 + t * 8);
    ushort8 u1 = *reinterpret_cast<const ushort8*>(Wu1 + 2048 + t * 8);
    *reinterpret_cast<ushort8*>(&smem[0][t * 8]) = g0;
    *reinterpret_cast<ushort8*>(&smem[0][2048 + t * 8]) = g1;
    *reinterpret_cast<ushort8*>(&smem[0][4096 + t * 8]) = u0;
    *reinterpret_cast<ushort8*>(&smem[0][6144 + t * 8]) = u1;
  }

#pragma unroll
  for (int kt = 0; kt < 16; ++kt) {
    const int cb = kt & 1, nb = cb ^ 1;
    __syncthreads();
    // issue next-kt staging loads (independent of compute)
    ushort8 ng0, ng1, nu0, nu1;
    if (kt < 15) {
      const unsigned short* gG = Wg + (kt + 1) * 4096;
      const unsigned short* gU = Wu1 + (kt + 1) * 4096;
      ng0 = *reinterpret_cast<const ushort8*>(gG + t * 8);
      ng1 = *reinterpret_cast<const ushort8*>(gG + 2048 + t * 8);
      nu0 = *reinterpret_cast<const ushort8*>(gU + t * 8);
      nu1 = *reinterpret_cast<const ushort8*>(gU + 2048 + t * 8);
    }
    // A fragment
    const unsigned short* S = (kt < 4) ? xb : (kt < 8) ? Ml : (kt < 12) ? Mm : Mg;
    int cbase = ((kt & 3) << 5) + (lgp << 3);
    bf16x8 a = (bf16x8){0, 0, 0, 0, 0, 0, 0, 0};
    if (aok) a = *reinterpret_cast<const bf16x8*>(S + (long)arow * HH + cbase);
    // MFMA from LDS
#pragma unroll
    for (int nt = 0; nt < 8; ++nt) {
      bf16x8 bgf = *reinterpret_cast<const bf16x8*>(&smem[cb][nt * 512 + lane * 8]);
      accG[nt] = __builtin_amdgcn_mfma_f32_16x16x32_bf16(a, bgf, accG[nt], 0, 0, 0);
      bf16x8 buf_ = *reinterpret_cast<const bf16x8*>(&smem[cb][4096 + nt * 512 + lane * 8]);
      accH[nt] = __builtin_amdgcn_mfma_f32_16x16x32_bf16(a, buf_, accH[nt], 0, 0, 0);
    }
    // write next buffer
    if (kt < 15) {
      *reinterpret_cast<ushort8*>(&smem[nb][t * 8]) = ng0;
      *reinterpret_cast<ushort8*>(&smem[nb][2048 + t * 8]) = ng1;
      *reinterpret_cast<ushort8*>(&smem[nb][4096 + t * 8]) = nu0;
      *reinterpret_cast<ushort8*>(&smem[nb][6144 + t * 8]) = nu1;
    }
  }
  __syncthreads();  // done with staging buffers -> reuse as Hs

  unsigned short (*Hs)[136] = reinterpret_cast<unsigned short(*)[136]>(&smem[0][0]);

#pragma unroll
  for (int nt = 0; nt < 8; ++nt) {
    int col = nt * 16 + lr;
    float bgv = bg[col], bhv = bu1[col];
#pragma unroll
    for (int r = 0; r < 4; ++r) {
      float g = 1.f / (1.f + __expf(-(accG[nt][r] + bgv)));
      accG[nt][r] = g;
      float h = fmaxf(accH[nt][r] + bhv, 0.f);
      Hs[wave * 16 + lgp * 4 + r][col] = f2bf(h);
    }
  }

  f32x4 accU[8];
#pragma unroll
  for (int nt = 0; nt < 8; ++nt) accU[nt] = (f32x4){0.f, 0.f, 0.f, 0.f};
#pragma unroll
  for (int kt = 0; kt < 4; ++kt) {
    bf16x8 a = *reinterpret_cast<const bf16x8*>(&Hs[wave * 16 + lr][kt * 32 + lgp * 8]);
#pragma unroll
    for (int nt = 0; nt < 8; ++nt) {
      accU[nt] = __builtin_amdgcn_mfma_f32_16x16x32_bf16(a, bfrag(Wu2, kt, nt, lane), accU[nt], 0, 0, 0);
    }
  }

#pragma unroll
  for (int nt = 0; nt < 8; ++nt) {
    int col = nt * 16 + lr;
    float b2v = bu2[col];
#pragma unroll
    for (int r = 0; r < 4; ++r) {
      int row = n0 + wave * 16 + lgp * 4 + r;
      float xv = (row < NN) ? x[(long)row * HH + col] : 0.f;
      float u = accU[nt][r] + b2v;
      float g = accG[nt][r];
      accU[nt][r] = g * u + (1.f - g) * xv;
    }
  }

#pragma unroll
  for (int r = 0; r < 4; ++r) {
    int row = n0 + wave * 16 + lgp * 4 + r;
    float s = 0.f;
#pragma unroll
    for (int nt = 0; nt < 8; ++nt) s += accU[nt][r];
    s += __shfl_xor(s, 1, 64);
    s += __shfl_xor(s, 2, 64);
    s += __shfl_xor(s, 4, 64);
    s += __shfl_xor(s, 8, 64);
    float mu = s * (1.f / 128.f);
    float qv = 0.f;
#pragma unroll
    for (int nt = 0; nt < 8; ++nt) {
      float d = accU[nt][r] - mu;
      qv += d * d;
    }
    qv += __shfl_xor(qv, 1, 64);
    qv += __shfl_xor(qv, 2, 64);
    qv += __shfl_xor(qv, 4, 64);
    qv += __shfl_xor(qv, 8, 64);
    float rs = rsqrtf(qv * (1.f / 128.f) + 1e-5f);
    if (row < NN) {
#pragma unroll
      for (int nt = 0; nt < 8; ++nt) {
        int col = nt * 16 + lr;
        out[(long)row * HH + col] = (accU[nt][r] - mu) * rs * gamma[col] + beta[col];
      }
    }
  }
}

extern "C" void kernel_launch(void* const* d_in, const int* in_sizes, int n_in,
                              void* d_out, int out_size, void* d_ws, size_t ws_size,
                              hipStream_t stream) {
  const float* x = (const float*)d_in[0];
  const int* ei_l = (const int*)d_in[1];
  const float* ea_l = (const float*)d_in[2];
  const int* ei_m = (const int*)d_in[3];
  const float* ea_m = (const float*)d_in[4];
  const int* ei_g = (const int*)d_in[5];
  const float* ea_g = (const float*)d_in[6];
  const float* Wa1 = (const float*)d_in[7];
  const float* ba1 = (const float*)d_in[8];
  const float* Wa2 = (const float*)d_in[9];
  const float* ba2 = (const float*)d_in[10];
  const float* Wb1 = (const float*)d_in[11];
  const float* bb1 = (const float*)d_in[12];
  const float* Wb2 = (const float*)d_in[13];
  const float* bb2 = (const float*)d_in[14];
  const float* Wc1 = (const float*)d_in[15];
  const float* bc1 = (const float*)d_in[16];
  const float* Wc2 = (const float*)d_in[17];
  const float* bc2 = (const float*)d_in[18];
  const float* Wg = (const float*)d_in[19];
  const float* bg = (const float*)d_in[20];
  const float* Wu1 = (const float*)d_in[21];
  const float* bu1 = (const float*)d_in[22];
  const float* Wu2 = (const float*)d_in[23];
  const float* bu2 = (const float*)d_in[24];
  const float* gamma = (const float*)d_in[25];
  const float* beta = (const float*)d_in[26];

  const int El = in_sizes[1] / 2;
  const int Em = in_sizes[3] / 2;
  const int Eg = in_sizes[5] / 2;
  const int Etot = El + Em + Eg;

  // Workspace layout (hagg bf16)
  unsigned short* wp = (unsigned short*)d_ws;
  unsigned short* hl = wp; wp += (size_t)NN * HH;
  unsigned short* hm = wp; wp += (size_t)NN * HH;
  unsigned short* hg = wp; wp += (size_t)NN * HH;
  unsigned short* W1a_a = wp; wp += 128 * 128;
  unsigned short* W1b_a = wp; wp += 128 * 128;
  unsigned short* W2_a  = wp; wp += 128 * 128;
  unsigned short* W1a_b = wp; wp += 128 * 128;
  unsigned short* W1b_b = wp; wp += 128 * 128;
  unsigned short* W2_b  = wp; wp += 128 * 128;
  unsigned short* W1a_c = wp; wp += 128 * 128;
  unsigned short* W1b_c = wp; wp += 128 * 128;
  unsigned short* W2_c  = wp; wp += 128 * 128;
  unsigned short* Wu2_s = wp; wp += 128 * 128;
  unsigned short* Wg_s  = wp; wp += 512 * 128;
  unsigned short* Wu1_s = wp; wp += 512 * 128;
  unsigned short* xb  = wp; wp += (size_t)NN * HH;
  unsigned short* P_l = wp; wp += (size_t)NN * HH;
  unsigned short* Q_l = wp; wp += (size_t)NN * HH;
  unsigned short* P_m = wp; wp += (size_t)NN * HH;
  unsigned short* Q_m = wp; wp += (size_t)NN * HH;
  unsigned short* P_g = wp; wp += (size_t)NN * HH;
  unsigned short* Q_g = wp; wp += (size_t)NN * HH;
  unsigned short* M_l = P_l;   // alias (P dead after edge_kernel)
  unsigned short* M_m = P_m;
  unsigned short* M_g = P_g;
  int* ip = (int*)wp;
  int* cnt    = ip; ip += 3 * NN;   // degrees (kept)
  int* offs   = ip; ip += 3 * NN;   // consumed by scatter
  int* rowptr = ip; ip += 3 * NN;   // kept for edge kernel
  int* bsum   = ip; ip += 256;
  size_t off16 = ((size_t)((char*)ip - (char*)d_ws) + 15) & ~(size_t)15;
  float4* sed = (float4*)((char*)d_ws + off16);   // Etot packed records

  hipMemsetAsync(cnt, 0, 3 * NN * sizeof(int), stream);

  // Weight swizzles
  SwzJobs jobs;
  jobs.src[0] = Wa1;            jobs.dst[0] = W1a_a;
  jobs.src[1] = Wa1 + 128*128;  jobs.dst[1] = W1b_a;
  jobs.src[2] = Wa2;            jobs.dst[2] = W2_a;
  jobs.src[3] = Wb1;            jobs.dst[3] = W1a_b;
  jobs.src[4] = Wb1 + 128*128;  jobs.dst[4] = W1b_b;
  jobs.src[5] = Wb2;            jobs.dst[5] = W2_b;
  jobs.src[6] = Wc1;            jobs.dst[6] = W1a_c;
  jobs.src[7] = Wc1 + 128*128;  jobs.dst[7] = W1b_c;
  jobs.src[8] = Wc2;            jobs.dst[8] = W2_c;
  jobs.src[9] = Wu2;            jobs.dst[9] = Wu2_s;
  jobs.src[10] = Wg;            jobs.dst[10] = Wg_s;
  jobs.src[11] = Wu1;           jobs.dst[11] = Wu1_s;
  swz_all_kernel<<<640 + 512, 256, 0, stream>>>(jobs);

  // P/Q precompute (P = x@W1a; Q = x@W1b + b1) + xb write-out; jb split across blocks
  PQJobs pq;
  pq.Wswz[0] = W1a_a; pq.bias[0] = nullptr; pq.out[0] = P_l;
  pq.Wswz[1] = W1b_a; pq.bias[1] = ba1;     pq.out[1] = Q_l;
  pq.Wswz[2] = W1a_b; pq.bias[2] = nullptr; pq.out[2] = P_m;
  pq.Wswz[3] = W1b_b; pq.bias[3] = bb1;     pq.out[3] = Q_m;
  pq.Wswz[4] = W1a_c; pq.bias[4] = nullptr; pq.out[4] = P_g;
  pq.Wswz[5] = W1b_c; pq.bias[5] = bc1;     pq.out[5] = Q_g;
  const int NB = (NN + 63) / 64;
  pq_kernel<<<NB * 6, 256, 0, stream>>>(x, xb, pq);

  // Counting sort by dst (packed sed + rowptr)
  hist3_kernel<<<(Etot + 255) / 256, 256, 0, stream>>>(ei_l, ei_m, ei_g, El, Em, Eg, cnt);
  const int n3 = 3 * NN;
  const int nblkA = (n3 + 1023) / 1024;
  scanA_kernel<<<nblkA, 1024, 0, stream>>>(cnt, offs, bsum, n3);
  scanB_kernel<<<1, 256, 0, stream>>>(bsum, nblkA);
  scanC_kernel<<<nblkA, 1024, 0, stream>>>(offs, rowptr, bsum, n3);
  scatter3_kernel<<<(Etot + 255) / 256, 256, 0, stream>>>(
      ei_l, ei_m, ei_g, ea_l, ea_m, ea_g, El, Em, Eg, offs, sed);

  // Edge pass: one wave per dst, scalarized metadata, plain bf16 stores
  EParams2 ep;
  ep.s[0] = {P_l, Q_l, Wa1 + 256 * 128, hl};
  ep.s[1] = {P_m, Q_m, Wb1 + 256 * 128, hm};
  ep.s[2] = {P_g, Q_g, Wc1 + 256 * 128, hg};
  ep.sed = sed; ep.rowptr = rowptr; ep.cnt = cnt;
  edge_kernel<<<(3 * NN + 3) / 4, 256, 0, stream>>>(ep);

  // Msg pass: M_s = bf16(hagg_s @ W2_s + deg*b2_s)
  MsgParams mp;
  mp.s[0] = {hl, W2_a, ba2, cnt,          M_l};
  mp.s[1] = {hm, W2_b, bb2, cnt + NN,     M_m};
  mp.s[2] = {hg, W2_c, bc2, cnt + 2 * NN, M_g};
  msg_kernel<<<3 * NB, 256, 0, stream>>>(mp);

  // Node update + LayerNorm (LDS-staged B, double-buffered)
  node_kernel<<<NB, 256, 0, stream>>>(x, xb, M_l, M_m, M_g, Wg_s, Wu1_s, Wu2_s,
                                      bg, bu1, bu2, gamma, beta, (float*)d_out);
}

// Round 13
// 330.455 us; speedup vs baseline: 1.3359x; 1.0325x over previous
//
#include <hip/hip_runtime.h>

typedef __attribute__((ext_vector_type(8))) short bf16x8;
typedef __attribute__((ext_vector_type(8))) unsigned short ushort8;
typedef __attribute__((ext_vector_type(4))) float f32x4;

#define NN 50000
#define HH 128

static __device__ __forceinline__ unsigned short f2bf(float f) {
  unsigned u = __builtin_bit_cast(unsigned, f);
  u = u + 0x7FFFu + ((u >> 16) & 1u);
  return (unsigned short)(u >> 16);
}

static __device__ __forceinline__ float bf2f(unsigned short b) {
  return __builtin_bit_cast(float, ((unsigned)b) << 16);
}

static __device__ __forceinline__ bf16x8 bfrag(const unsigned short* __restrict__ w,
                                               int kt, int nt, int lane) {
  return *reinterpret_cast<const bf16x8*>(w + (((kt * 8 + nt) * 64 + lane) << 3));
}

// x (fp32) -> xb (bf16), 8 elems/thread
__global__ void cvt_x_kernel(const float* __restrict__ x, unsigned short* __restrict__ xb,
                             int total8) {
  int i = blockIdx.x * 256 + threadIdx.x;
  if (i >= total8) return;
  const float4* p = reinterpret_cast<const float4*>(x + (long)i * 8);
  float4 f0 = p[0], f1 = p[1];
  ushort8 u;
  u[0] = f2bf(f0.x); u[1] = f2bf(f0.y); u[2] = f2bf(f0.z); u[3] = f2bf(f0.w);
  u[4] = f2bf(f1.x); u[5] = f2bf(f1.y); u[6] = f2bf(f1.z); u[7] = f2bf(f1.w);
  *reinterpret_cast<ushort8*>(xb + (long)i * 8) = u;
}

// Fused weight swizzle: 10 jobs with K=128 (64 blocks each), 2 jobs with K=512 (256 blocks).
struct SwzJobs {
  const float* src[12];
  unsigned short* dst[12];
};
__global__ void swz_all_kernel(SwzJobs jobs) {
  int b = blockIdx.x;
  int job, blk;
  if (b < 640) { job = b >> 6; blk = b & 63; }
  else { b -= 640; job = 10 + (b >> 8); blk = b & 255; }
  int o = blk * 256 + threadIdx.x;
  int j = o & 7, lane = (o >> 3) & 63, nt = (o >> 9) & 7, kt = o >> 12;
  int row = kt * 32 + (lane >> 4) * 8 + j;
  int col = nt * 16 + (lane & 15);
  jobs.dst[job][o] = f2bf(jobs.src[job][row * 128 + col]);
}

// P/Q precompute (msg-style): out = xb @ W (+bias), A-frags direct from global bf16.
struct PQJobs {
  const unsigned short* Wswz[6];
  const float* bias[6];
  unsigned short* out[6];
};
__global__ __launch_bounds__(256) void pq_kernel(const unsigned short* __restrict__ xb,
                                                 PQJobs jobs) {
  const int bid = blockIdx.x;
  const int jb = bid % 6;
  const int n0 = (bid / 6) * 64;
  const int t = threadIdx.x;
  const int wave = t >> 6, lane = t & 63;
  const int lr = lane & 15, lgp = lane >> 4;
  const int arow = n0 + wave * 16 + lr;
  const bool aok = arow < NN;
  const unsigned short* W = jobs.Wswz[jb];
  f32x4 acc[8];
#pragma unroll
  for (int nt = 0; nt < 8; ++nt) acc[nt] = (f32x4){0.f, 0.f, 0.f, 0.f};
#pragma unroll
  for (int kt = 0; kt < 4; ++kt) {
    bf16x8 a = (bf16x8){0, 0, 0, 0, 0, 0, 0, 0};
    if (aok)
      a = *reinterpret_cast<const bf16x8*>(xb + (long)arow * HH + kt * 32 + lgp * 8);
#pragma unroll
    for (int nt = 0; nt < 8; ++nt)
      acc[nt] = __builtin_amdgcn_mfma_f32_16x16x32_bf16(
          a, bfrag(W, kt, nt, lane), acc[nt], 0, 0, 0);
  }
  const float* bi = jobs.bias[jb];
  unsigned short* O = jobs.out[jb];
#pragma unroll
  for (int nt = 0; nt < 8; ++nt) {
    int col = nt * 16 + lr;
    float bv = bi ? bi[col] : 0.f;
#pragma unroll
    for (int r = 0; r < 4; ++r) {
      int row = n0 + wave * 16 + lgp * 4 + r;
      if (row < NN) O[(long)row * HH + col] = f2bf(acc[nt][r] + bv);
    }
  }
}

// ---- counting-sort by destination (two-level parallel scan) ----
__global__ void hist3_kernel(const int* __restrict__ eiL, const int* __restrict__ eiM,
                             const int* __restrict__ eiG, int El, int Em, int Eg,
                             int* __restrict__ cnt) {
  int e = blockIdx.x * 256 + threadIdx.x;
  const int* ei; int E, off;
  if (e < El) { ei = eiL; E = El; off = 0; }
  else if (e < El + Em) { e -= El; ei = eiM; E = Em; off = NN; }
  else { e -= El + Em; if (e >= Eg) return; ei = eiG; E = Eg; off = 2 * NN; }
  atomicAdd(cnt + off + ei[E + e], 1);
}

__global__ void scanA_kernel(const int* __restrict__ cnt, int* __restrict__ offs,
                             int* __restrict__ bsum, int n) {
  const int t = threadIdx.x, lane = t & 63, w = t >> 6;
  const int i = blockIdx.x * 1024 + t;
  __shared__ int wsum[16], wpre[16];
  int v = (i < n) ? cnt[i] : 0;
  int inc = v;
#pragma unroll
  for (int d = 1; d < 64; d <<= 1) {
    int o = __shfl_up(inc, d, 64);
    if (lane >= d) inc += o;
  }
  if (lane == 63) wsum[w] = inc;
  __syncthreads();
  if (t == 0) {
    int run = 0;
#pragma unroll
    for (int k = 0; k < 16; ++k) { wpre[k] = run; run += wsum[k]; }
    wsum[0] = run;
  }
  __syncthreads();
  if (i < n) offs[i] = wpre[w] + inc - v;
  if (t == 0) bsum[blockIdx.x] = wsum[0];
}

__global__ void scanB_kernel(int* __restrict__ bsum, int n) {
  const int t = threadIdx.x, lane = t & 63, w = t >> 6;
  __shared__ int wsum[4];
  int v = (t < n) ? bsum[t] : 0;
  int inc = v;
#pragma unroll
  for (int d = 1; d < 64; d <<= 1) {
    int o = __shfl_up(inc, d, 64);
    if (lane >= d) inc += o;
  }
  if (lane == 63) wsum[w] = inc;
  __syncthreads();
  int wo = 0;
  for (int k = 0; k < w; ++k) wo += wsum[k];
  if (t < n) bsum[t] = wo + inc - v;
}

__global__ void scanC_kernel(int* __restrict__ offs, int* __restrict__ rowptr,
                             const int* __restrict__ bsum, int n) {
  int i = blockIdx.x * 1024 + threadIdx.x;
  if (i < n) {
    int v = offs[i] + bsum[blockIdx.x];
    offs[i] = v;
    rowptr[i] = v;
  }
}

// Scatter: packed 16B record {src_bits, ea0, ea1, ea2} at dst-sorted position.
__global__ void scatter3_kernel(const int* __restrict__ eiL, const int* __restrict__ eiM,
                                const int* __restrict__ eiG,
                                const float* __restrict__ eaL, const float* __restrict__ eaM,
                                const float* __restrict__ eaG,
                                int El, int Em, int Eg, int* __restrict__ offs,
                                float4* __restrict__ sed) {
  int e = blockIdx.x * 256 + threadIdx.x;
  const int* ei; const float* ea; int E, off;
  if (e < El) { ei = eiL; ea = eaL; E = El; off = 0; }
  else if (e < El + Em) { e -= El; ei = eiM; ea = eaM; E = Em; off = NN; }
  else { e -= El + Em; if (e >= Eg) return; ei = eiG; ea = eaG; E = Eg; off = 2 * NN; }
  int d = ei[E + e];
  int p = atomicAdd(offs + off + d, 1);
  sed[p] = make_float4(__int_as_float(ei[e]),
                       ea[(long)e * 3 + 0], ea[(long)e * 3 + 1], ea[(long)e * 3 + 2]);
}

// ---- edge kernel: one WAVE per dst (CSR run), scalarized metadata.
struct EScale2 { const unsigned short *P, *Q; const float* Wc; unsigned short* hag; };
struct EParams2 {
  EScale2 s[3];
  const float4* sed;
  const int* rowptr; const int* cnt;
};
__global__ __launch_bounds__(256) void edge_kernel(EParams2 prm) {
  const int t = threadIdx.x;
  const int wave = t >> 6, lane = t & 63;
  int gidv = blockIdx.x * 4 + wave;
  if (gidv >= 3 * NN) return;
  const int gid = __builtin_amdgcn_readfirstlane(gidv);
  const int si = (gid >= NN) + (gid >= 2 * NN);
  const int dst = gid - si * NN;
  const EScale2 S = prm.s[si];
  const int base = __builtin_amdgcn_readfirstlane(prm.rowptr[gid]);
  const int len = __builtin_amdgcn_readfirstlane(prm.cnt[gid]);
  const int c2 = lane * 2;

  const float wcA0 = S.Wc[c2],       wcB0 = S.Wc[c2 + 1];
  const float wcA1 = S.Wc[128 + c2], wcB1 = S.Wc[129 + c2];
  const float wcA2 = S.Wc[256 + c2], wcB2 = S.Wc[257 + c2];

  float aA0 = 0.f, aB0 = 0.f, aA1 = 0.f, aB1 = 0.f;
  if (len > 0) {
    ushort2 qv = *reinterpret_cast<const ushort2*>(S.Q + (long)dst * HH + c2);
    const float qA = bf2f(qv.x), qB = bf2f(qv.y);
    const float4* __restrict__ ep = prm.sed + base;
    int i = 0;
    for (; i + 4 <= len; i += 4) {
      float4 m0 = ep[i], m1 = ep[i + 1], m2 = ep[i + 2], m3 = ep[i + 3];
      ushort2 p0 = *reinterpret_cast<const ushort2*>(S.P + (long)__float_as_int(m0.x) * HH + c2);
      ushort2 p1 = *reinterpret_cast<const ushort2*>(S.P + (long)__float_as_int(m1.x) * HH + c2);
      ushort2 p2 = *reinterpret_cast<const ushort2*>(S.P + (long)__float_as_int(m2.x) * HH + c2);
      ushort2 p3 = *reinterpret_cast<const ushort2*>(S.P + (long)__float_as_int(m3.x) * HH + c2);
      aA0 += fmaxf(bf2f(p0.x) + qA + m0.y * wcA0 + m0.z * wcA1 + m0.w * wcA2, 0.f);
      aB0 += fmaxf(bf2f(p0.y) + qB + m0.y * wcB0 + m0.z * wcB1 + m0.w * wcB2, 0.f);
      aA1 += fmaxf(bf2f(p1.x) + qA + m1.y * wcA0 + m1.z * wcA1 + m1.w * wcA2, 0.f);
      aB1 += fmaxf(bf2f(p1.y) + qB + m1.y * wcB0 + m1.z * wcB1 + m1.w * wcB2, 0.f);
      aA0 += fmaxf(bf2f(p2.x) + qA + m2.y * wcA0 + m2.z * wcA1 + m2.w * wcA2, 0.f);
      aB0 += fmaxf(bf2f(p2.y) + qB + m2.y * wcB0 + m2.z * wcB1 + m2.w * wcB2, 0.f);
      aA1 += fmaxf(bf2f(p3.x) + qA + m3.y * wcA0 + m3.z * wcA1 + m3.w * wcA2, 0.f);
      aB1 += fmaxf(bf2f(p3.y) + qB + m3.y * wcB0 + m3.z * wcB1 + m3.w * wcB2, 0.f);
    }
    for (; i < len; ++i) {
      float4 m0 = ep[i];
      ushort2 p0 = *reinterpret_cast<const ushort2*>(S.P + (long)__float_as_int(m0.x) * HH + c2);
      aA0 += fmaxf(bf2f(p0.x) + qA + m0.y * wcA0 + m0.z * wcA1 + m0.w * wcA2, 0.f);
      aB0 += fmaxf(bf2f(p0.y) + qB + m0.y * wcB0 + m0.z * wcB1 + m0.w * wcB2, 0.f);
    }
  }
  *reinterpret_cast<ushort2*>(S.hag + (long)dst * HH + c2) =
      make_ushort2(f2bf(aA0 + aA1), f2bf(aB0 + aB1));
}

// ---- msg kernel: M_s = bf16(hagg_s @ W2_s + deg_s*b2_s) ----
struct MsgScale {
  const unsigned short* H; const unsigned short* W2s; const float* b2; const int* deg;
  unsigned short* M;
};
struct MsgParams { MsgScale s[3]; };
__global__ __launch_bounds__(256) void msg_kernel(MsgParams prm) {
  const int bid = blockIdx.x;
  const int si = bid % 3;
  const int n0 = (bid / 3) * 64;
  const MsgScale S = prm.s[si];
  const int t = threadIdx.x;
  const int wave = t >> 6, lane = t & 63;
  const int lr = lane & 15, lgp = lane >> 4;
  const int arow = n0 + wave * 16 + lr;
  const bool aok = arow < NN;
  f32x4 acc[8];
#pragma unroll
  for (int nt = 0; nt < 8; ++nt) acc[nt] = (f32x4){0.f, 0.f, 0.f, 0.f};
#pragma unroll
  for (int kt = 0; kt < 4; ++kt) {
    bf16x8 a = (bf16x8){0, 0, 0, 0, 0, 0, 0, 0};
    if (aok)
      a = *reinterpret_cast<const bf16x8*>(S.H + (long)arow * HH + kt * 32 + lgp * 8);
#pragma unroll
    for (int nt = 0; nt < 8; ++nt)
      acc[nt] = __builtin_amdgcn_mfma_f32_16x16x32_bf16(
          a, bfrag(S.W2s, kt, nt, lane), acc[nt], 0, 0, 0);
  }
#pragma unroll
  for (int nt = 0; nt < 8; ++nt) {
    int col = nt * 16 + lr;
    float bv = S.b2[col];
#pragma unroll
    for (int r = 0; r < 4; ++r) {
      int row = n0 + wave * 16 + lgp * 4 + r;
      if (row < NN) {
        float dg = (float)S.deg[row];
        S.M[(long)row * HH + col] = f2bf(acc[nt][r] + dg * bv);
      }
    }
  }
}

// ---- node kernel: K=512 streaming GEMM with double-buffered LDS B-staging ----
__global__ __launch_bounds__(256) void node_kernel(
    const float* __restrict__ x, const unsigned short* __restrict__ xb,
    const unsigned short* __restrict__ Ml, const unsigned short* __restrict__ Mm,
    const unsigned short* __restrict__ Mg,
    const unsigned short* __restrict__ Wg, const unsigned short* __restrict__ Wu1,
    const unsigned short* __restrict__ Wu2,
    const float* __restrict__ bg, const float* __restrict__ bu1, const float* __restrict__ bu2,
    const float* __restrict__ gamma, const float* __restrict__ beta,
    float* __restrict__ out) {
  __shared__ unsigned short smem[2][8192];
  const int t = threadIdx.x;
  const int n0 = blockIdx.x * 64;
  const int wave = t >> 6, lane = t & 63;
  const int lr = lane & 15, lgp = lane >> 4;
  const int arow = n0 + wave * 16 + lr;
  const bool aok = arow < NN;

  f32x4 accG[8], accH[8];
#pragma unroll
  for (int nt = 0; nt < 8; ++nt) {
    accG[nt] = (f32x4){0.f, 0.f, 0.f, 0.f};
    accH[nt] = (f32x4){0.f, 0.f, 0.f, 0.f};
  }

  {
    ushort8 g0 = *reinterpret_cast<const ushort8*>(Wg + t * 8);
    ushort8 g1 = *reinterpret_cast<const ushort8*>(Wg + 2048 + t * 8);
    ushort8 u0 = *reinterpret_cast<const ushort8*>(Wu1 + t * 8);
    ushort8 u1 = *reinterpret_cast<const ushort8*>(Wu1 + 2048 + t * 8);
    *reinterpret_cast<ushort8*>(&smem[0][t * 8]) = g0;
    *reinterpret_cast<ushort8*>(&smem[0][2048 + t * 8]) = g1;
    *reinterpret_cast<ushort8*>(&smem[0][4096 + t * 8]) = u0;
    *reinterpret_cast<ushort8*>(&smem[0][6144 + t * 8]) = u1;
  }

#pragma unroll
  for (int kt = 0; kt < 16; ++kt) {
    const int cb = kt & 1, nb = cb ^ 1;
    __syncthreads();
    ushort8 ng0, ng1, nu0, nu1;
    if (kt < 15) {
      const unsigned short* gG = Wg + (kt + 1) * 4096;
      const unsigned short* gU = Wu1 + (kt + 1) * 4096;
      ng0 = *reinterpret_cast<const ushort8*>(gG + t * 8);
      ng1 = *reinterpret_cast<const ushort8*>(gG + 2048 + t * 8);
      nu0 = *reinterpret_cast<const ushort8*>(gU + t * 8);
      nu1 = *reinterpret_cast<const ushort8*>(gU + 2048 + t * 8);
    }
    const unsigned short* S = (kt < 4) ? xb : (kt < 8) ? Ml : (kt < 12) ? Mm : Mg;
    int cbase = ((kt & 3) << 5) + (lgp << 3);
    bf16x8 a = (bf16x8){0, 0, 0, 0, 0, 0, 0, 0};
    if (aok) a = *reinterpret_cast<const bf16x8*>(S + (long)arow * HH + cbase);
#pragma unroll
    for (int nt = 0; nt < 8; ++nt) {
      bf16x8 bgf = *reinterpret_cast<const bf16x8*>(&smem[cb][nt * 512 + lane * 8]);
      accG[nt] = __builtin_amdgcn_mfma_f32_16x16x32_bf16(a, bgf, accG[nt], 0, 0, 0);
      bf16x8 buf_ = *reinterpret_cast<const bf16x8*>(&smem[cb][4096 + nt * 512 + lane * 8]);
      accH[nt] = __builtin_amdgcn_mfma_f32_16x16x32_bf16(a, buf_, accH[nt], 0, 0, 0);
    }
    if (kt < 15) {
      *reinterpret_cast<ushort8*>(&smem[nb][t * 8]) = ng0;
      *reinterpret_cast<ushort8*>(&smem[nb][2048 + t * 8]) = ng1;
      *reinterpret_cast<ushort8*>(&smem[nb][4096 + t * 8]) = nu0;
      *reinterpret_cast<ushort8*>(&smem[nb][6144 + t * 8]) = nu1;
    }
  }
  __syncthreads();

  unsigned short (*Hs)[136] = reinterpret_cast<unsigned short(*)[136]>(&smem[0][0]);

#pragma unroll
  for (int nt = 0; nt < 8; ++nt) {
    int col = nt * 16 + lr;
    float bgv = bg[col], bhv = bu1[col];
#pragma unroll
    for (int r = 0; r < 4; ++r) {
      float g = 1.f / (1.f + __expf(-(accG[nt][r] + bgv)));
      accG[nt][r] = g;
      float h = fmaxf(accH[nt][r] + bhv, 0.f);
      Hs[wave * 16 + lgp * 4 + r][col] = f2bf(h);
    }
  }

  f32x4 accU[8];
#pragma unroll
  for (int nt = 0; nt < 8; ++nt) accU[nt] = (f32x4){0.f, 0.f, 0.f, 0.f};
#pragma unroll
  for (int kt = 0; kt < 4; ++kt) {
    bf16x8 a = *reinterpret_cast<const bf16x8*>(&Hs[wave * 16 + lr][kt * 32 + lgp * 8]);
#pragma unroll
    for (int nt = 0; nt < 8; ++nt) {
      accU[nt] = __builtin_amdgcn_mfma_f32_16x16x32_bf16(a, bfrag(Wu2, kt, nt, lane), accU[nt], 0, 0, 0);
    }
  }

#pragma unroll
  for (int nt = 0; nt < 8; ++nt) {
    int col = nt * 16 + lr;
    float b2v = bu2[col];
#pragma unroll
    for (int r = 0; r < 4; ++r) {
      int row = n0 + wave * 16 + lgp * 4 + r;
      float xv = (row < NN) ? x[(long)row * HH + col] : 0.f;
      float u = accU[nt][r] + b2v;
      float g = accG[nt][r];
      accU[nt][r] = g * u + (1.f - g) * xv;
    }
  }

#pragma unroll
  for (int r = 0; r < 4; ++r) {
    int row = n0 + wave * 16 + lgp * 4 + r;
    float s = 0.f;
#pragma unroll
    for (int nt = 0; nt < 8; ++nt) s += accU[nt][r];
    s += __shfl_xor(s, 1, 64);
    s += __shfl_xor(s, 2, 64);
    s += __shfl_xor(s, 4, 64);
    s += __shfl_xor(s, 8, 64);
    float mu = s * (1.f / 128.f);
    float qv = 0.f;
#pragma unroll
    for (int nt = 0; nt < 8; ++nt) {
      float d = accU[nt][r] - mu;
      qv += d * d;
    }
    qv += __shfl_xor(qv, 1, 64);
    qv += __shfl_xor(qv, 2, 64);
    qv += __shfl_xor(qv, 4, 64);
    qv += __shfl_xor(qv, 8, 64);
    float rs = rsqrtf(qv * (1.f / 128.f) + 1e-5f);
    if (row < NN) {
#pragma unroll
      for (int nt = 0; nt < 8; ++nt) {
        int col = nt * 16 + lr;
        out[(long)row * HH + col] = (accU[nt][r] - mu) * rs * gamma[col] + beta[col];
      }
    }
  }
}

extern "C" void kernel_launch(void* const* d_in, const int* in_sizes, int n_in,
                              void* d_out, int out_size, void* d_ws, size_t ws_size,
                              hipStream_t stream) {
  const float* x = (const float*)d_in[0];
  const int* ei_l = (const int*)d_in[1];
  const float* ea_l = (const float*)d_in[2];
  const int* ei_m = (const int*)d_in[3];
  const float* ea_m = (const float*)d_in[4];
  const int* ei_g = (const int*)d_in[5];
  const float* ea_g = (const float*)d_in[6];
  const float* Wa1 = (const float*)d_in[7];
  const float* ba1 = (const float*)d_in[8];
  const float* Wa2 = (const float*)d_in[9];
  const float* ba2 = (const float*)d_in[10];
  const float* Wb1 = (const float*)d_in[11];
  const float* bb1 = (const float*)d_in[12];
  const float* Wb2 = (const float*)d_in[13];
  const float* bb2 = (const float*)d_in[14];
  const float* Wc1 = (const float*)d_in[15];
  const float* bc1 = (const float*)d_in[16];
  const float* Wc2 = (const float*)d_in[17];
  const float* bc2 = (const float*)d_in[18];
  const float* Wg = (const float*)d_in[19];
  const float* bg = (const float*)d_in[20];
  const float* Wu1 = (const float*)d_in[21];
  const float* bu1 = (const float*)d_in[22];
  const float* Wu2 = (const float*)d_in[23];
  const float* bu2 = (const float*)d_in[24];
  const float* gamma = (const float*)d_in[25];
  const float* beta = (const float*)d_in[26];

  const int El = in_sizes[1] / 2;
  const int Em = in_sizes[3] / 2;
  const int Eg = in_sizes[5] / 2;
  const int Etot = El + Em + Eg;

  // Workspace layout (hagg bf16)
  unsigned short* wp = (unsigned short*)d_ws;
  unsigned short* hl = wp; wp += (size_t)NN * HH;
  unsigned short* hm = wp; wp += (size_t)NN * HH;
  unsigned short* hg = wp; wp += (size_t)NN * HH;
  unsigned short* W1a_a = wp; wp += 128 * 128;
  unsigned short* W1b_a = wp; wp += 128 * 128;
  unsigned short* W2_a  = wp; wp += 128 * 128;
  unsigned short* W1a_b = wp; wp += 128 * 128;
  unsigned short* W1b_b = wp; wp += 128 * 128;
  unsigned short* W2_b  = wp; wp += 128 * 128;
  unsigned short* W1a_c = wp; wp += 128 * 128;
  unsigned short* W1b_c = wp; wp += 128 * 128;
  unsigned short* W2_c  = wp; wp += 128 * 128;
  unsigned short* Wu2_s = wp; wp += 128 * 128;
  unsigned short* Wg_s  = wp; wp += 512 * 128;
  unsigned short* Wu1_s = wp; wp += 512 * 128;
  unsigned short* xb  = wp; wp += (size_t)NN * HH;
  unsigned short* P_l = wp; wp += (size_t)NN * HH;
  unsigned short* Q_l = wp; wp += (size_t)NN * HH;
  unsigned short* P_m = wp; wp += (size_t)NN * HH;
  unsigned short* Q_m = wp; wp += (size_t)NN * HH;
  unsigned short* P_g = wp; wp += (size_t)NN * HH;
  unsigned short* Q_g = wp; wp += (size_t)NN * HH;
  unsigned short* M_l = P_l;   // alias (P dead after edge_kernel)
  unsigned short* M_m = P_m;
  unsigned short* M_g = P_g;
  int* ip = (int*)wp;
  int* cnt    = ip; ip += 3 * NN;   // degrees (kept)
  int* offs   = ip; ip += 3 * NN;   // consumed by scatter
  int* rowptr = ip; ip += 3 * NN;   // kept for edge kernel
  int* bsum   = ip; ip += 256;
  size_t off16 = ((size_t)((char*)ip - (char*)d_ws) + 15) & ~(size_t)15;
  float4* sed = (float4*)((char*)d_ws + off16);   // Etot packed records

  hipMemsetAsync(cnt, 0, 3 * NN * sizeof(int), stream);

  // x -> bf16 (once)
  cvt_x_kernel<<<(NN * HH / 8 + 255) / 256, 256, 0, stream>>>(x, xb, NN * HH / 8);

  // Weight swizzles
  SwzJobs jobs;
  jobs.src[0] = Wa1;            jobs.dst[0] = W1a_a;
  jobs.src[1] = Wa1 + 128*128;  jobs.dst[1] = W1b_a;
  jobs.src[2] = Wa2;            jobs.dst[2] = W2_a;
  jobs.src[3] = Wb1;            jobs.dst[3] = W1a_b;
  jobs.src[4] = Wb1 + 128*128;  jobs.dst[4] = W1b_b;
  jobs.src[5] = Wb2;            jobs.dst[5] = W2_b;
  jobs.src[6] = Wc1;            jobs.dst[6] = W1a_c;
  jobs.src[7] = Wc1 + 128*128;  jobs.dst[7] = W1b_c;
  jobs.src[8] = Wc2;            jobs.dst[8] = W2_c;
  jobs.src[9] = Wu2;            jobs.dst[9] = Wu2_s;
  jobs.src[10] = Wg;            jobs.dst[10] = Wg_s;
  jobs.src[11] = Wu1;           jobs.dst[11] = Wu1_s;
  swz_all_kernel<<<640 + 512, 256, 0, stream>>>(jobs);

  // P/Q precompute (msg-style, direct bf16 A from xb)
  PQJobs pq;
  pq.Wswz[0] = W1a_a; pq.bias[0] = nullptr; pq.out[0] = P_l;
  pq.Wswz[1] = W1b_a; pq.bias[1] = ba1;     pq.out[1] = Q_l;
  pq.Wswz[2] = W1a_b; pq.bias[2] = nullptr; pq.out[2] = P_m;
  pq.Wswz[3] = W1b_b; pq.bias[3] = bb1;     pq.out[3] = Q_m;
  pq.Wswz[4] = W1a_c; pq.bias[4] = nullptr; pq.out[4] = P_g;
  pq.Wswz[5] = W1b_c; pq.bias[5] = bc1;     pq.out[5] = Q_g;
  const int NB = (NN + 63) / 64;
  pq_kernel<<<NB * 6, 256, 0, stream>>>(xb, pq);

  // Counting sort by dst (packed sed + rowptr)
  hist3_kernel<<<(Etot + 255) / 256, 256, 0, stream>>>(ei_l, ei_m, ei_g, El, Em, Eg, cnt);
  const int n3 = 3 * NN;
  const int nblkA = (n3 + 1023) / 1024;
  scanA_kernel<<<nblkA, 1024, 0, stream>>>(cnt, offs, bsum, n3);
  scanB_kernel<<<1, 256, 0, stream>>>(bsum, nblkA);
  scanC_kernel<<<nblkA, 1024, 0, stream>>>(offs, rowptr, bsum, n3);
  scatter3_kernel<<<(Etot + 255) / 256, 256, 0, stream>>>(
      ei_l, ei_m, ei_g, ea_l, ea_m, ea_g, El, Em, Eg, offs, sed);

  // Edge pass: one wave per dst, scalarized metadata, plain bf16 stores
  EParams2 ep;
  ep.s[0] = {P_l, Q_l, Wa1 + 256 * 128, hl};
  ep.s[1] = {P_m, Q_m, Wb1 + 256 * 128, hm};
  ep.s[2] = {P_g, Q_g, Wc1 + 256 * 128, hg};
  ep.sed = sed; ep.rowptr = rowptr; ep.cnt = cnt;
  edge_kernel<<<(3 * NN + 3) / 4, 256, 0, stream>>>(ep);

  // Msg pass: M_s = bf16(hagg_s @ W2_s + deg*b2_s)
  MsgParams mp;
  mp.s[0] = {hl, W2_a, ba2, cnt,          M_l};
  mp.s[1] = {hm, W2_b, bb2, cnt + NN,     M_m};
  mp.s[2] = {hg, W2_c, bc2, cnt + 2 * NN, M_g};
  msg_kernel<<<3 * NB, 256, 0, stream>>>(mp);

  // Node update + LayerNorm (LDS-staged B, double-buffered)
  node_kernel<<<NB, 256, 0, stream>>>(x, xb, M_l, M_m, M_g, Wg_s, Wu1_s, Wu2_s,
                                      bg, bu1, bu2, gamma, beta, (float*)d_out);
}

// Round 14
// 308.756 us; speedup vs baseline: 1.4298x; 1.0703x over previous
//
#include <hip/hip_runtime.h>

typedef __attribute__((ext_vector_type(8))) short bf16x8;
typedef __attribute__((ext_vector_type(8))) unsigned short ushort8;
typedef __attribute__((ext_vector_type(4))) float f32x4;

#define NN 50000
#define HH 128

static __device__ __forceinline__ unsigned short f2bf(float f) {
  unsigned u = __builtin_bit_cast(unsigned, f);
  u = u + 0x7FFFu + ((u >> 16) & 1u);
  return (unsigned short)(u >> 16);
}

static __device__ __forceinline__ float bf2f(unsigned short b) {
  return __builtin_bit_cast(float, ((unsigned)b) << 16);
}

static __device__ __forceinline__ bf16x8 bfrag(const unsigned short* __restrict__ w,
                                               int kt, int nt, int lane) {
  return *reinterpret_cast<const bf16x8*>(w + (((kt * 8 + nt) * 64 + lane) << 3));
}

struct SwzJobs {
  const float* src[12];
  unsigned short* dst[12];
};

// ---- prep kernel: cvt_x ∪ weight-swizzle ∪ hist3, fused by block range ----
struct PrepParams {
  const float* x; unsigned short* xb; int total8; int cvtBlocks;
  SwzJobs swz; int swzBlocks;   // 1152: 10x64 K=128 + 2x256 K=512
  const int *eiL, *eiM, *eiG; int El, Em, Eg; int* cnt;
};
__global__ __launch_bounds__(256) void prep_kernel(PrepParams p) {
  const int t = threadIdx.x;
  int b = blockIdx.x;
  if (b < p.cvtBlocks) {
    int i = b * 256 + t;
    if (i >= p.total8) return;
    const float4* pp = reinterpret_cast<const float4*>(p.x + (long)i * 8);
    float4 f0 = pp[0], f1 = pp[1];
    ushort8 u;
    u[0] = f2bf(f0.x); u[1] = f2bf(f0.y); u[2] = f2bf(f0.z); u[3] = f2bf(f0.w);
    u[4] = f2bf(f1.x); u[5] = f2bf(f1.y); u[6] = f2bf(f1.z); u[7] = f2bf(f1.w);
    *reinterpret_cast<ushort8*>(p.xb + (long)i * 8) = u;
    return;
  }
  b -= p.cvtBlocks;
  if (b < p.swzBlocks) {
    int job, blk;
    if (b < 640) { job = b >> 6; blk = b & 63; }
    else { b -= 640; job = 10 + (b >> 8); blk = b & 255; }
    int o = blk * 256 + t;
    int j = o & 7, lane = (o >> 3) & 63, nt = (o >> 9) & 7, kt = o >> 12;
    int row = kt * 32 + (lane >> 4) * 8 + j;
    int col = nt * 16 + (lane & 15);
    p.swz.dst[job][o] = f2bf(p.swz.src[job][row * 128 + col]);
    return;
  }
  b -= p.swzBlocks;
  int e = b * 256 + t;
  const int* ei; int E, off;
  if (e < p.El) { ei = p.eiL; E = p.El; off = 0; }
  else if (e < p.El + p.Em) { e -= p.El; ei = p.eiM; E = p.Em; off = NN; }
  else { e -= p.El + p.Em; if (e >= p.Eg) return; ei = p.eiG; E = p.Eg; off = 2 * NN; }
  atomicAdd(p.cnt + off + ei[E + e], 1);
}

// ---- scan kernels (two-level) ----
__global__ void scanA_kernel(const int* __restrict__ cnt, int* __restrict__ offs,
                             int* __restrict__ bsum, int n) {
  const int t = threadIdx.x, lane = t & 63, w = t >> 6;
  const int i = blockIdx.x * 1024 + t;
  __shared__ int wsum[16], wpre[16];
  int v = (i < n) ? cnt[i] : 0;
  int inc = v;
#pragma unroll
  for (int d = 1; d < 64; d <<= 1) {
    int o = __shfl_up(inc, d, 64);
    if (lane >= d) inc += o;
  }
  if (lane == 63) wsum[w] = inc;
  __syncthreads();
  if (t == 0) {
    int run = 0;
#pragma unroll
    for (int k = 0; k < 16; ++k) { wpre[k] = run; run += wsum[k]; }
    wsum[0] = run;
  }
  __syncthreads();
  if (i < n) offs[i] = wpre[w] + inc - v;
  if (t == 0) bsum[blockIdx.x] = wsum[0];
}

__global__ void scanB_kernel(int* __restrict__ bsum, int n) {
  const int t = threadIdx.x, lane = t & 63, w = t >> 6;
  __shared__ int wsum[4];
  int v = (t < n) ? bsum[t] : 0;
  int inc = v;
#pragma unroll
  for (int d = 1; d < 64; d <<= 1) {
    int o = __shfl_up(inc, d, 64);
    if (lane >= d) inc += o;
  }
  if (lane == 63) wsum[w] = inc;
  __syncthreads();
  int wo = 0;
  for (int k = 0; k < w; ++k) wo += wsum[k];
  if (t < n) bsum[t] = wo + inc - v;
}

__global__ void scanC_kernel(int* __restrict__ offs, int* __restrict__ rowptr,
                             const int* __restrict__ bsum, int n) {
  int i = blockIdx.x * 1024 + threadIdx.x;
  if (i < n) {
    int v = offs[i] + bsum[blockIdx.x];
    offs[i] = v;
    rowptr[i] = v;
  }
}

// ---- fused scatter ∪ pq kernel ----
// scatter: packed 8B record {src:u16, ea0,ea1,ea2: bf16} at dst-sorted position.
// pq: out = xb @ W (+bias), msg-style.
struct PQJobs {
  const unsigned short* Wswz[6];
  const float* bias[6];
  unsigned short* out[6];
};
struct SpqParams {
  // scatter
  const int *eiL, *eiM, *eiG;
  const float *eaL, *eaM, *eaG;
  int El, Em, Eg; int* offs; ushort4* sed; int scatterBlocks;
  // pq
  const unsigned short* xb; PQJobs pq;
};
__global__ __launch_bounds__(256) void spq_kernel(SpqParams p) {
  const int t = threadIdx.x;
  if (blockIdx.x < p.scatterBlocks) {
    int e = blockIdx.x * 256 + t;
    const int* ei; const float* ea; int E, off;
    if (e < p.El) { ei = p.eiL; ea = p.eaL; E = p.El; off = 0; }
    else if (e < p.El + p.Em) { e -= p.El; ei = p.eiM; ea = p.eaM; E = p.Em; off = NN; }
    else { e -= p.El + p.Em; if (e >= p.Eg) return; ei = p.eiG; ea = p.eaG; E = p.Eg; off = 2 * NN; }
    int d = ei[E + e];
    int pos = atomicAdd(p.offs + off + d, 1);
    ushort4 r;
    r.x = (unsigned short)ei[e];
    r.y = f2bf(ea[(long)e * 3 + 0]);
    r.z = f2bf(ea[(long)e * 3 + 1]);
    r.w = f2bf(ea[(long)e * 3 + 2]);
    p.sed[pos] = r;
    return;
  }
  const int bid = blockIdx.x - p.scatterBlocks;
  const int jb = bid % 6;
  const int n0 = (bid / 6) * 64;
  const int wave = t >> 6, lane = t & 63;
  const int lr = lane & 15, lgp = lane >> 4;
  const int arow = n0 + wave * 16 + lr;
  const bool aok = arow < NN;
  const unsigned short* W = p.pq.Wswz[jb];
  f32x4 acc[8];
#pragma unroll
  for (int nt = 0; nt < 8; ++nt) acc[nt] = (f32x4){0.f, 0.f, 0.f, 0.f};
#pragma unroll
  for (int kt = 0; kt < 4; ++kt) {
    bf16x8 a = (bf16x8){0, 0, 0, 0, 0, 0, 0, 0};
    if (aok)
      a = *reinterpret_cast<const bf16x8*>(p.xb + (long)arow * HH + kt * 32 + lgp * 8);
#pragma unroll
    for (int nt = 0; nt < 8; ++nt)
      acc[nt] = __builtin_amdgcn_mfma_f32_16x16x32_bf16(
          a, bfrag(W, kt, nt, lane), acc[nt], 0, 0, 0);
  }
  const float* bi = p.pq.bias[jb];
  unsigned short* O = p.pq.out[jb];
#pragma unroll
  for (int nt = 0; nt < 8; ++nt) {
    int col = nt * 16 + lr;
    float bv = bi ? bi[col] : 0.f;
#pragma unroll
    for (int r = 0; r < 4; ++r) {
      int row = n0 + wave * 16 + lgp * 4 + r;
      if (row < NN) O[(long)row * HH + col] = f2bf(acc[nt][r] + bv);
    }
  }
}

// ---- edge kernel: one WAVE per dst (CSR run), 8B packed records ----
struct EScale2 { const unsigned short *P, *Q; const float* Wc; unsigned short* hag; };
struct EParams2 {
  EScale2 s[3];
  const ushort4* sed;
  const int* rowptr; const int* cnt;
};
__global__ __launch_bounds__(256) void edge_kernel(EParams2 prm) {
  const int t = threadIdx.x;
  const int wave = t >> 6, lane = t & 63;
  int gidv = blockIdx.x * 4 + wave;
  if (gidv >= 3 * NN) return;
  const int gid = __builtin_amdgcn_readfirstlane(gidv);
  const int si = (gid >= NN) + (gid >= 2 * NN);
  const int dst = gid - si * NN;
  const EScale2 S = prm.s[si];
  const int base = __builtin_amdgcn_readfirstlane(prm.rowptr[gid]);
  const int len = __builtin_amdgcn_readfirstlane(prm.cnt[gid]);
  const int c2 = lane * 2;

  const float wcA0 = S.Wc[c2],       wcB0 = S.Wc[c2 + 1];
  const float wcA1 = S.Wc[128 + c2], wcB1 = S.Wc[129 + c2];
  const float wcA2 = S.Wc[256 + c2], wcB2 = S.Wc[257 + c2];

  float aA0 = 0.f, aB0 = 0.f, aA1 = 0.f, aB1 = 0.f;
  if (len > 0) {
    ushort2 qv = *reinterpret_cast<const ushort2*>(S.Q + (long)dst * HH + c2);
    const float qA = bf2f(qv.x), qB = bf2f(qv.y);
    const ushort4* __restrict__ ep = prm.sed + base;
    int i = 0;
    for (; i + 4 <= len; i += 4) {
      ushort4 m0 = ep[i], m1 = ep[i + 1], m2 = ep[i + 2], m3 = ep[i + 3];
      ushort2 p0 = *reinterpret_cast<const ushort2*>(S.P + (long)m0.x * HH + c2);
      ushort2 p1 = *reinterpret_cast<const ushort2*>(S.P + (long)m1.x * HH + c2);
      ushort2 p2 = *reinterpret_cast<const ushort2*>(S.P + (long)m2.x * HH + c2);
      ushort2 p3 = *reinterpret_cast<const ushort2*>(S.P + (long)m3.x * HH + c2);
      float e0x = bf2f(m0.y), e0y = bf2f(m0.z), e0z = bf2f(m0.w);
      float e1x = bf2f(m1.y), e1y = bf2f(m1.z), e1z = bf2f(m1.w);
      float e2x = bf2f(m2.y), e2y = bf2f(m2.z), e2z = bf2f(m2.w);
      float e3x = bf2f(m3.y), e3y = bf2f(m3.z), e3z = bf2f(m3.w);
      aA0 += fmaxf(bf2f(p0.x) + qA + e0x * wcA0 + e0y * wcA1 + e0z * wcA2, 0.f);
      aB0 += fmaxf(bf2f(p0.y) + qB + e0x * wcB0 + e0y * wcB1 + e0z * wcB2, 0.f);
      aA1 += fmaxf(bf2f(p1.x) + qA + e1x * wcA0 + e1y * wcA1 + e1z * wcA2, 0.f);
      aB1 += fmaxf(bf2f(p1.y) + qB + e1x * wcB0 + e1y * wcB1 + e1z * wcB2, 0.f);
      aA0 += fmaxf(bf2f(p2.x) + qA + e2x * wcA0 + e2y * wcA1 + e2z * wcA2, 0.f);
      aB0 += fmaxf(bf2f(p2.y) + qB + e2x * wcB0 + e2y * wcB1 + e2z * wcB2, 0.f);
      aA1 += fmaxf(bf2f(p3.x) + qA + e3x * wcA0 + e3y * wcA1 + e3z * wcA2, 0.f);
      aB1 += fmaxf(bf2f(p3.y) + qB + e3x * wcB0 + e3y * wcB1 + e3z * wcB2, 0.f);
    }
    for (; i < len; ++i) {
      ushort4 m0 = ep[i];
      ushort2 p0 = *reinterpret_cast<const ushort2*>(S.P + (long)m0.x * HH + c2);
      float e0x = bf2f(m0.y), e0y = bf2f(m0.z), e0z = bf2f(m0.w);
      aA0 += fmaxf(bf2f(p0.x) + qA + e0x * wcA0 + e0y * wcA1 + e0z * wcA2, 0.f);
      aB0 += fmaxf(bf2f(p0.y) + qB + e0x * wcB0 + e0y * wcB1 + e0z * wcB2, 0.f);
    }
  }
  *reinterpret_cast<ushort2*>(S.hag + (long)dst * HH + c2) =
      make_ushort2(f2bf(aA0 + aA1), f2bf(aB0 + aB1));
}

// ---- msg kernel: M_s = bf16(hagg_s @ W2_s + deg_s*b2_s) ----
struct MsgScale {
  const unsigned short* H; const unsigned short* W2s; const float* b2; const int* deg;
  unsigned short* M;
};
struct MsgParams { MsgScale s[3]; };
__global__ __launch_bounds__(256) void msg_kernel(MsgParams prm) {
  const int bid = blockIdx.x;
  const int si = bid % 3;
  const int n0 = (bid / 3) * 64;
  const MsgScale S = prm.s[si];
  const int t = threadIdx.x;
  const int wave = t >> 6, lane = t & 63;
  const int lr = lane & 15, lgp = lane >> 4;
  const int arow = n0 + wave * 16 + lr;
  const bool aok = arow < NN;
  f32x4 acc[8];
#pragma unroll
  for (int nt = 0; nt < 8; ++nt) acc[nt] = (f32x4){0.f, 0.f, 0.f, 0.f};
#pragma unroll
  for (int kt = 0; kt < 4; ++kt) {
    bf16x8 a = (bf16x8){0, 0, 0, 0, 0, 0, 0, 0};
    if (aok)
      a = *reinterpret_cast<const bf16x8*>(S.H + (long)arow * HH + kt * 32 + lgp * 8);
#pragma unroll
    for (int nt = 0; nt < 8; ++nt)
      acc[nt] = __builtin_amdgcn_mfma_f32_16x16x32_bf16(
          a, bfrag(S.W2s, kt, nt, lane), acc[nt], 0, 0, 0);
  }
#pragma unroll
  for (int nt = 0; nt < 8; ++nt) {
    int col = nt * 16 + lr;
    float bv = S.b2[col];
#pragma unroll
    for (int r = 0; r < 4; ++r) {
      int row = n0 + wave * 16 + lgp * 4 + r;
      if (row < NN) {
        float dg = (float)S.deg[row];
        S.M[(long)row * HH + col] = f2bf(acc[nt][r] + dg * bv);
      }
    }
  }
}

// ---- node kernel: K=512 streaming GEMM with double-buffered LDS B-staging ----
__global__ __launch_bounds__(256) void node_kernel(
    const float* __restrict__ x, const unsigned short* __restrict__ xb,
    const unsigned short* __restrict__ Ml, const unsigned short* __restrict__ Mm,
    const unsigned short* __restrict__ Mg,
    const unsigned short* __restrict__ Wg, const unsigned short* __restrict__ Wu1,
    const unsigned short* __restrict__ Wu2,
    const float* __restrict__ bg, const float* __restrict__ bu1, const float* __restrict__ bu2,
    const float* __restrict__ gamma, const float* __restrict__ beta,
    float* __restrict__ out) {
  __shared__ unsigned short smem[2][8192];
  const int t = threadIdx.x;
  const int n0 = blockIdx.x * 64;
  const int wave = t >> 6, lane = t & 63;
  const int lr = lane & 15, lgp = lane >> 4;
  const int arow = n0 + wave * 16 + lr;
  const bool aok = arow < NN;

  f32x4 accG[8], accH[8];
#pragma unroll
  for (int nt = 0; nt < 8; ++nt) {
    accG[nt] = (f32x4){0.f, 0.f, 0.f, 0.f};
    accH[nt] = (f32x4){0.f, 0.f, 0.f, 0.f};
  }

  {
    ushort8 g0 = *reinterpret_cast<const ushort8*>(Wg + t * 8);
    ushort8 g1 = *reinterpret_cast<const ushort8*>(Wg + 2048 + t * 8);
    ushort8 u0 = *reinterpret_cast<const ushort8*>(Wu1 + t * 8);
    ushort8 u1 = *reinterpret_cast<const ushort8*>(Wu1 + 2048 + t * 8);
    *reinterpret_cast<ushort8*>(&smem[0][t * 8]) = g0;
    *reinterpret_cast<ushort8*>(&smem[0][2048 + t * 8]) = g1;
    *reinterpret_cast<ushort8*>(&smem[0][4096 + t * 8]) = u0;
    *reinterpret_cast<ushort8*>(&smem[0][6144 + t * 8]) = u1;
  }

#pragma unroll
  for (int kt = 0; kt < 16; ++kt) {
    const int cb = kt & 1, nb = cb ^ 1;
    __syncthreads();
    ushort8 ng0, ng1, nu0, nu1;
    if (kt < 15) {
      const unsigned short* gG = Wg + (kt + 1) * 4096;
      const unsigned short* gU = Wu1 + (kt + 1) * 4096;
      ng0 = *reinterpret_cast<const ushort8*>(gG + t * 8);
      ng1 = *reinterpret_cast<const ushort8*>(gG + 2048 + t * 8);
      nu0 = *reinterpret_cast<const ushort8*>(gU + t * 8);
      nu1 = *reinterpret_cast<const ushort8*>(gU + 2048 + t * 8);
    }
    const unsigned short* S = (kt < 4) ? xb : (kt < 8) ? Ml : (kt < 12) ? Mm : Mg;
    int cbase = ((kt & 3) << 5) + (lgp << 3);
    bf16x8 a = (bf16x8){0, 0, 0, 0, 0, 0, 0, 0};
    if (aok) a = *reinterpret_cast<const bf16x8*>(S + (long)arow * HH + cbase);
#pragma unroll
    for (int nt = 0; nt < 8; ++nt) {
      bf16x8 bgf = *reinterpret_cast<const bf16x8*>(&smem[cb][nt * 512 + lane * 8]);
      accG[nt] = __builtin_amdgcn_mfma_f32_16x16x32_bf16(a, bgf, accG[nt], 0, 0, 0);
      bf16x8 buf_ = *reinterpret_cast<const bf16x8*>(&smem[cb][4096 + nt * 512 + lane * 8]);
      accH[nt] = __builtin_amdgcn_mfma_f32_16x16x32_bf16(a, buf_, accH[nt], 0, 0, 0);
    }
    if (kt < 15) {
      *reinterpret_cast<ushort8*>(&smem[nb][t * 8]) = ng0;
      *reinterpret_cast<ushort8*>(&smem[nb][2048 + t * 8]) = ng1;
      *reinterpret_cast<ushort8*>(&smem[nb][4096 + t * 8]) = nu0;
      *reinterpret_cast<ushort8*>(&smem[nb][6144 + t * 8]) = nu1;
    }
  }
  __syncthreads();

  unsigned short (*Hs)[136] = reinterpret_cast<unsigned short(*)[136]>(&smem[0][0]);

#pragma unroll
  for (int nt = 0; nt < 8; ++nt) {
    int col = nt * 16 + lr;
    float bgv = bg[col], bhv = bu1[col];
#pragma unroll
    for (int r = 0; r < 4; ++r) {
      float g = 1.f / (1.f + __expf(-(accG[nt][r] + bgv)));
      accG[nt][r] = g;
      float h = fmaxf(accH[nt][r] + bhv, 0.f);
      Hs[wave * 16 + lgp * 4 + r][col] = f2bf(h);
    }
  }

  f32x4 accU[8];
#pragma unroll
  for (int nt = 0; nt < 8; ++nt) accU[nt] = (f32x4){0.f, 0.f, 0.f, 0.f};
#pragma unroll
  for (int kt = 0; kt < 4; ++kt) {
    bf16x8 a = *reinterpret_cast<const bf16x8*>(&Hs[wave * 16 + lr][kt * 32 + lgp * 8]);
#pragma unroll
    for (int nt = 0; nt < 8; ++nt) {
      accU[nt] = __builtin_amdgcn_mfma_f32_16x16x32_bf16(a, bfrag(Wu2, kt, nt, lane), accU[nt], 0, 0, 0);
    }
  }

#pragma unroll
  for (int nt = 0; nt < 8; ++nt) {
    int col = nt * 16 + lr;
    float b2v = bu2[col];
#pragma unroll
    for (int r = 0; r < 4; ++r) {
      int row = n0 + wave * 16 + lgp * 4 + r;
      float xv = (row < NN) ? x[(long)row * HH + col] : 0.f;
      float u = accU[nt][r] + b2v;
      float g = accG[nt][r];
      accU[nt][r] = g * u + (1.f - g) * xv;
    }
  }

#pragma unroll
  for (int r = 0; r < 4; ++r) {
    int row = n0 + wave * 16 + lgp * 4 + r;
    float s = 0.f;
#pragma unroll
    for (int nt = 0; nt < 8; ++nt) s += accU[nt][r];
    s += __shfl_xor(s, 1, 64);
    s += __shfl_xor(s, 2, 64);
    s += __shfl_xor(s, 4, 64);
    s += __shfl_xor(s, 8, 64);
    float mu = s * (1.f / 128.f);
    float qv = 0.f;
#pragma unroll
    for (int nt = 0; nt < 8; ++nt) {
      float d = accU[nt][r] - mu;
      qv += d * d;
    }
    qv += __shfl_xor(qv, 1, 64);
    qv += __shfl_xor(qv, 2, 64);
    qv += __shfl_xor(qv, 4, 64);
    qv += __shfl_xor(qv, 8, 64);
    float rs = rsqrtf(qv * (1.f / 128.f) + 1e-5f);
    if (row < NN) {
#pragma unroll
      for (int nt = 0; nt < 8; ++nt) {
        int col = nt * 16 + lr;
        out[(long)row * HH + col] = (accU[nt][r] - mu) * rs * gamma[col] + beta[col];
      }
    }
  }
}

extern "C" void kernel_launch(void* const* d_in, const int* in_sizes, int n_in,
                              void* d_out, int out_size, void* d_ws, size_t ws_size,
                              hipStream_t stream) {
  const float* x = (const float*)d_in[0];
  const int* ei_l = (const int*)d_in[1];
  const float* ea_l = (const float*)d_in[2];
  const int* ei_m = (const int*)d_in[3];
  const float* ea_m = (const float*)d_in[4];
  const int* ei_g = (const int*)d_in[5];
  const float* ea_g = (const float*)d_in[6];
  const float* Wa1 = (const float*)d_in[7];
  const float* ba1 = (const float*)d_in[8];
  const float* Wa2 = (const float*)d_in[9];
  const float* ba2 = (const float*)d_in[10];
  const float* Wb1 = (const float*)d_in[11];
  const float* bb1 = (const float*)d_in[12];
  const float* Wb2 = (const float*)d_in[13];
  const float* bb2 = (const float*)d_in[14];
  const float* Wc1 = (const float*)d_in[15];
  const float* bc1 = (const float*)d_in[16];
  const float* Wc2 = (const float*)d_in[17];
  const float* bc2 = (const float*)d_in[18];
  const float* Wg = (const float*)d_in[19];
  const float* bg = (const float*)d_in[20];
  const float* Wu1 = (const float*)d_in[21];
  const float* bu1 = (const float*)d_in[22];
  const float* Wu2 = (const float*)d_in[23];
  const float* bu2 = (const float*)d_in[24];
  const float* gamma = (const float*)d_in[25];
  const float* beta = (const float*)d_in[26];

  const int El = in_sizes[1] / 2;
  const int Em = in_sizes[3] / 2;
  const int Eg = in_sizes[5] / 2;
  const int Etot = El + Em + Eg;

  // Workspace layout (hagg bf16)
  unsigned short* wp = (unsigned short*)d_ws;
  unsigned short* hl = wp; wp += (size_t)NN * HH;
  unsigned short* hm = wp; wp += (size_t)NN * HH;
  unsigned short* hg = wp; wp += (size_t)NN * HH;
  unsigned short* W1a_a = wp; wp += 128 * 128;
  unsigned short* W1b_a = wp; wp += 128 * 128;
  unsigned short* W2_a  = wp; wp += 128 * 128;
  unsigned short* W1a_b = wp; wp += 128 * 128;
  unsigned short* W1b_b = wp; wp += 128 * 128;
  unsigned short* W2_b  = wp; wp += 128 * 128;
  unsigned short* W1a_c = wp; wp += 128 * 128;
  unsigned short* W1b_c = wp; wp += 128 * 128;
  unsigned short* W2_c  = wp; wp += 128 * 128;
  unsigned short* Wu2_s = wp; wp += 128 * 128;
  unsigned short* Wg_s  = wp; wp += 512 * 128;
  unsigned short* Wu1_s = wp; wp += 512 * 128;
  unsigned short* xb  = wp; wp += (size_t)NN * HH;
  unsigned short* P_l = wp; wp += (size_t)NN * HH;
  unsigned short* Q_l = wp; wp += (size_t)NN * HH;
  unsigned short* P_m = wp; wp += (size_t)NN * HH;
  unsigned short* Q_m = wp; wp += (size_t)NN * HH;
  unsigned short* P_g = wp; wp += (size_t)NN * HH;
  unsigned short* Q_g = wp; wp += (size_t)NN * HH;
  unsigned short* M_l = P_l;   // alias (P dead after edge_kernel)
  unsigned short* M_m = P_m;
  unsigned short* M_g = P_g;
  int* ip = (int*)wp;
  int* cnt    = ip; ip += 3 * NN;   // degrees (kept)
  int* offs   = ip; ip += 3 * NN;   // consumed by scatter
  int* rowptr = ip; ip += 3 * NN;   // kept for edge kernel
  int* bsum   = ip; ip += 256;
  size_t off16 = ((size_t)((char*)ip - (char*)d_ws) + 15) & ~(size_t)15;
  ushort4* sed = (ushort4*)((char*)d_ws + off16);   // Etot packed 8B records

  hipMemsetAsync(cnt, 0, 3 * NN * sizeof(int), stream);

  // prep: cvt_x ∪ swz ∪ hist (one launch)
  PrepParams pp;
  pp.x = x; pp.xb = xb; pp.total8 = NN * HH / 8;
  pp.cvtBlocks = (pp.total8 + 255) / 256;
  pp.swz.src[0] = Wa1;            pp.swz.dst[0] = W1a_a;
  pp.swz.src[1] = Wa1 + 128*128;  pp.swz.dst[1] = W1b_a;
  pp.swz.src[2] = Wa2;            pp.swz.dst[2] = W2_a;
  pp.swz.src[3] = Wb1;            pp.swz.dst[3] = W1a_b;
  pp.swz.src[4] = Wb1 + 128*128;  pp.swz.dst[4] = W1b_b;
  pp.swz.src[5] = Wb2;            pp.swz.dst[5] = W2_b;
  pp.swz.src[6] = Wc1;            pp.swz.dst[6] = W1a_c;
  pp.swz.src[7] = Wc1 + 128*128;  pp.swz.dst[7] = W1b_c;
  pp.swz.src[8] = Wc2;            pp.swz.dst[8] = W2_c;
  pp.swz.src[9] = Wu2;            pp.swz.dst[9] = Wu2_s;
  pp.swz.src[10] = Wg;            pp.swz.dst[10] = Wg_s;
  pp.swz.src[11] = Wu1;           pp.swz.dst[11] = Wu1_s;
  pp.swzBlocks = 640 + 512;
  pp.eiL = ei_l; pp.eiM = ei_m; pp.eiG = ei_g;
  pp.El = El; pp.Em = Em; pp.Eg = Eg; pp.cnt = cnt;
  const int histBlocks = (Etot + 255) / 256;
  prep_kernel<<<pp.cvtBlocks + pp.swzBlocks + histBlocks, 256, 0, stream>>>(pp);

  // scan
  const int n3 = 3 * NN;
  const int nblkA = (n3 + 1023) / 1024;
  scanA_kernel<<<nblkA, 1024, 0, stream>>>(cnt, offs, bsum, n3);
  scanB_kernel<<<1, 256, 0, stream>>>(bsum, nblkA);
  scanC_kernel<<<nblkA, 1024, 0, stream>>>(offs, rowptr, bsum, n3);

  // fused scatter ∪ pq
  SpqParams sp;
  sp.eiL = ei_l; sp.eiM = ei_m; sp.eiG = ei_g;
  sp.eaL = ea_l; sp.eaM = ea_m; sp.eaG = ea_g;
  sp.El = El; sp.Em = Em; sp.Eg = Eg;
  sp.offs = offs; sp.sed = sed;
  sp.scatterBlocks = (Etot + 255) / 256;
  sp.xb = xb;
  sp.pq.Wswz[0] = W1a_a; sp.pq.bias[0] = nullptr; sp.pq.out[0] = P_l;
  sp.pq.Wswz[1] = W1b_a; sp.pq.bias[1] = ba1;     sp.pq.out[1] = Q_l;
  sp.pq.Wswz[2] = W1a_b; sp.pq.bias[2] = nullptr; sp.pq.out[2] = P_m;
  sp.pq.Wswz[3] = W1b_b; sp.pq.bias[3] = bb1;     sp.pq.out[3] = Q_m;
  sp.pq.Wswz[4] = W1a_c; sp.pq.bias[4] = nullptr; sp.pq.out[4] = P_g;
  sp.pq.Wswz[5] = W1b_c; sp.pq.bias[5] = bc1;     sp.pq.out[5] = Q_g;
  const int NB = (NN + 63) / 64;
  spq_kernel<<<sp.scatterBlocks + NB * 6, 256, 0, stream>>>(sp);

  // Edge pass: one wave per dst, 8B records, plain bf16 stores
  EParams2 ep;
  ep.s[0] = {P_l, Q_l, Wa1 + 256 * 128, hl};
  ep.s[1] = {P_m, Q_m, Wb1 + 256 * 128, hm};
  ep.s[2] = {P_g, Q_g, Wc1 + 256 * 128, hg};
  ep.sed = sed; ep.rowptr = rowptr; ep.cnt = cnt;
  edge_kernel<<<(3 * NN + 3) / 4, 256, 0, stream>>>(ep);

  // Msg pass: M_s = bf16(hagg_s @ W2_s + deg*b2_s)
  MsgParams mp;
  mp.s[0] = {hl, W2_a, ba2, cnt,          M_l};
  mp.s[1] = {hm, W2_b, bb2, cnt + NN,     M_m};
  mp.s[2] = {hg, W2_c, bc2, cnt + 2 * NN, M_g};
  msg_kernel<<<3 * NB, 256, 0, stream>>>(mp);

  // Node update + LayerNorm (LDS-staged B, double-buffered)
  node_kernel<<<NB, 256, 0, stream>>>(x, xb, M_l, M_m, M_g, Wg_s, Wu1_s, Wu2_s,
                                      bg, bu1, bu2, gamma, beta, (float*)d_out);
}

// Round 15
// 278.898 us; speedup vs baseline: 1.5829x; 1.1071x over previous
//
#include <hip/hip_runtime.h>

typedef __attribute__((ext_vector_type(8))) short bf16x8;
typedef __attribute__((ext_vector_type(8))) unsigned short ushort8;
typedef __attribute__((ext_vector_type(4))) float f32x4;

#define NN 50000
#define HH 128

static __device__ __forceinline__ unsigned short f2bf(float f) {
  unsigned u = __builtin_bit_cast(unsigned, f);
  u = u + 0x7FFFu + ((u >> 16) & 1u);
  return (unsigned short)(u >> 16);
}

static __device__ __forceinline__ float bf2f(unsigned short b) {
  return __builtin_bit_cast(float, ((unsigned)b) << 16);
}

static __device__ __forceinline__ bf16x8 bfrag(const unsigned short* __restrict__ w,
                                               int kt, int nt, int lane) {
  return *reinterpret_cast<const bf16x8*>(w + (((kt * 8 + nt) * 64 + lane) << 3));
}

struct SwzJobs {
  const float* src[12];
  unsigned short* dst[12];
};

// ---- prep kernel: cvt_x ∪ weight-swizzle ∪ hist3(+rank record), fused by block range ----
struct PrepParams {
  const float* x; unsigned short* xb; int total8; int cvtBlocks;
  SwzJobs swz; int swzBlocks;   // 1152: 10x64 K=128 + 2x256 K=512
  const int *eiL, *eiM, *eiG; int El, Em, Eg; int* cnt; int* rk;
};
__global__ __launch_bounds__(256) void prep_kernel(PrepParams p) {
  const int t = threadIdx.x;
  int b = blockIdx.x;
  if (b < p.cvtBlocks) {
    int i = b * 256 + t;
    if (i >= p.total8) return;
    const float4* pp = reinterpret_cast<const float4*>(p.x + (long)i * 8);
    float4 f0 = pp[0], f1 = pp[1];
    ushort8 u;
    u[0] = f2bf(f0.x); u[1] = f2bf(f0.y); u[2] = f2bf(f0.z); u[3] = f2bf(f0.w);
    u[4] = f2bf(f1.x); u[5] = f2bf(f1.y); u[6] = f2bf(f1.z); u[7] = f2bf(f1.w);
    *reinterpret_cast<ushort8*>(p.xb + (long)i * 8) = u;
    return;
  }
  b -= p.cvtBlocks;
  if (b < p.swzBlocks) {
    int job, blk;
    if (b < 640) { job = b >> 6; blk = b & 63; }
    else { b -= 640; job = 10 + (b >> 8); blk = b & 255; }
    int o = blk * 256 + t;
    int j = o & 7, lane = (o >> 3) & 63, nt = (o >> 9) & 7, kt = o >> 12;
    int row = kt * 32 + (lane >> 4) * 8 + j;
    int col = nt * 16 + (lane & 15);
    p.swz.dst[job][o] = f2bf(p.swz.src[job][row * 128 + col]);
    return;
  }
  b -= p.swzBlocks;
  const int eg = b * 256 + t;   // concatenated edge index
  int e = eg;
  const int* ei; int E, off;
  if (e < p.El) { ei = p.eiL; E = p.El; off = 0; }
  else if (e < p.El + p.Em) { e -= p.El; ei = p.eiM; E = p.Em; off = NN; }
  else { e -= p.El + p.Em; if (e >= p.Eg) return; ei = p.eiG; E = p.Eg; off = 2 * NN; }
  int old = atomicAdd(p.cnt + off + ei[E + e], 1);
  p.rk[eg] = old;
}

// ---- scan kernels (two-level); final exclusive scan lands in rowptr ----
__global__ void scanA_kernel(const int* __restrict__ cnt, int* __restrict__ offs,
                             int* __restrict__ bsum, int n) {
  const int t = threadIdx.x, lane = t & 63, w = t >> 6;
  const int i = blockIdx.x * 1024 + t;
  __shared__ int wsum[16], wpre[16];
  int v = (i < n) ? cnt[i] : 0;
  int inc = v;
#pragma unroll
  for (int d = 1; d < 64; d <<= 1) {
    int o = __shfl_up(inc, d, 64);
    if (lane >= d) inc += o;
  }
  if (lane == 63) wsum[w] = inc;
  __syncthreads();
  if (t == 0) {
    int run = 0;
#pragma unroll
    for (int k = 0; k < 16; ++k) { wpre[k] = run; run += wsum[k]; }
    wsum[0] = run;
  }
  __syncthreads();
  if (i < n) offs[i] = wpre[w] + inc - v;
  if (t == 0) bsum[blockIdx.x] = wsum[0];
}

__global__ void scanB_kernel(int* __restrict__ bsum, int n) {
  const int t = threadIdx.x, lane = t & 63, w = t >> 6;
  __shared__ int wsum[4];
  int v = (t < n) ? bsum[t] : 0;
  int inc = v;
#pragma unroll
  for (int d = 1; d < 64; d <<= 1) {
    int o = __shfl_up(inc, d, 64);
    if (lane >= d) inc += o;
  }
  if (lane == 63) wsum[w] = inc;
  __syncthreads();
  int wo = 0;
  for (int k = 0; k < w; ++k) wo += wsum[k];
  if (t < n) bsum[t] = wo + inc - v;
}

__global__ void scanC_kernel(const int* __restrict__ offs, int* __restrict__ rowptr,
                             const int* __restrict__ bsum, int n) {
  int i = blockIdx.x * 1024 + threadIdx.x;
  if (i < n) rowptr[i] = offs[i] + bsum[blockIdx.x];
}

// ---- fused scatter ∪ pq kernel (scatter is ATOMIC-FREE: pos = rowptr[d] + rk[e]) ----
struct PQJobs {
  const unsigned short* Wswz[6];
  const float* bias[6];
  unsigned short* out[6];
};
struct SpqParams {
  const int *eiL, *eiM, *eiG;
  const float *eaL, *eaM, *eaG;
  int El, Em, Eg;
  const int* rowptr; const int* rk; ushort4* sed; int scatterBlocks;
  const unsigned short* xb; PQJobs pq;
};
__global__ __launch_bounds__(256) void spq_kernel(SpqParams p) {
  const int t = threadIdx.x;
  if (blockIdx.x < p.scatterBlocks) {
    const int eg = blockIdx.x * 256 + t;
    int e = eg;
    const int* ei; const float* ea; int E, off;
    if (e < p.El) { ei = p.eiL; ea = p.eaL; E = p.El; off = 0; }
    else if (e < p.El + p.Em) { e -= p.El; ei = p.eiM; ea = p.eaM; E = p.Em; off = NN; }
    else { e -= p.El + p.Em; if (e >= p.Eg) return; ei = p.eiG; ea = p.eaG; E = p.Eg; off = 2 * NN; }
    int d = ei[E + e];
    int pos = p.rowptr[off + d] + p.rk[eg];
    ushort4 r;
    r.x = (unsigned short)ei[e];
    r.y = f2bf(ea[(long)e * 3 + 0]);
    r.z = f2bf(ea[(long)e * 3 + 1]);
    r.w = f2bf(ea[(long)e * 3 + 2]);
    p.sed[pos] = r;
    return;
  }
  const int bid = blockIdx.x - p.scatterBlocks;
  const int jb = bid % 6;
  const int n0 = (bid / 6) * 64;
  const int wave = t >> 6, lane = t & 63;
  const int lr = lane & 15, lgp = lane >> 4;
  const int arow = n0 + wave * 16 + lr;
  const bool aok = arow < NN;
  const unsigned short* W = p.pq.Wswz[jb];
  f32x4 acc[8];
#pragma unroll
  for (int nt = 0; nt < 8; ++nt) acc[nt] = (f32x4){0.f, 0.f, 0.f, 0.f};
#pragma unroll
  for (int kt = 0; kt < 4; ++kt) {
    bf16x8 a = (bf16x8){0, 0, 0, 0, 0, 0, 0, 0};
    if (aok)
      a = *reinterpret_cast<const bf16x8*>(p.xb + (long)arow * HH + kt * 32 + lgp * 8);
#pragma unroll
    for (int nt = 0; nt < 8; ++nt)
      acc[nt] = __builtin_amdgcn_mfma_f32_16x16x32_bf16(
          a, bfrag(W, kt, nt, lane), acc[nt], 0, 0, 0);
  }
  const float* bi = p.pq.bias[jb];
  unsigned short* O = p.pq.out[jb];
#pragma unroll
  for (int nt = 0; nt < 8; ++nt) {
    int col = nt * 16 + lr;
    float bv = bi ? bi[col] : 0.f;
#pragma unroll
    for (int r = 0; r < 4; ++r) {
      int row = n0 + wave * 16 + lgp * 4 + r;
      if (row < NN) O[(long)row * HH + col] = f2bf(acc[nt][r] + bv);
    }
  }
}

// ---- edge kernel: one WAVE per dst (CSR run), 8B packed records ----
struct EScale2 { const unsigned short *P, *Q; const float* Wc; unsigned short* hag; };
struct EParams2 {
  EScale2 s[3];
  const ushort4* sed;
  const int* rowptr; const int* cnt;
};
__global__ __launch_bounds__(256) void edge_kernel(EParams2 prm) {
  const int t = threadIdx.x;
  const int wave = t >> 6, lane = t & 63;
  int gidv = blockIdx.x * 4 + wave;
  if (gidv >= 3 * NN) return;
  const int gid = __builtin_amdgcn_readfirstlane(gidv);
  const int si = (gid >= NN) + (gid >= 2 * NN);
  const int dst = gid - si * NN;
  const EScale2 S = prm.s[si];
  const int base = __builtin_amdgcn_readfirstlane(prm.rowptr[gid]);
  const int len = __builtin_amdgcn_readfirstlane(prm.cnt[gid]);
  const int c2 = lane * 2;

  const float wcA0 = S.Wc[c2],       wcB0 = S.Wc[c2 + 1];
  const float wcA1 = S.Wc[128 + c2], wcB1 = S.Wc[129 + c2];
  const float wcA2 = S.Wc[256 + c2], wcB2 = S.Wc[257 + c2];

  float aA0 = 0.f, aB0 = 0.f, aA1 = 0.f, aB1 = 0.f;
  if (len > 0) {
    ushort2 qv = *reinterpret_cast<const ushort2*>(S.Q + (long)dst * HH + c2);
    const float qA = bf2f(qv.x), qB = bf2f(qv.y);
    const ushort4* __restrict__ ep = prm.sed + base;
    int i = 0;
    for (; i + 4 <= len; i += 4) {
      ushort4 m0 = ep[i], m1 = ep[i + 1], m2 = ep[i + 2], m3 = ep[i + 3];
      ushort2 p0 = *reinterpret_cast<const ushort2*>(S.P + (long)m0.x * HH + c2);
      ushort2 p1 = *reinterpret_cast<const ushort2*>(S.P + (long)m1.x * HH + c2);
      ushort2 p2 = *reinterpret_cast<const ushort2*>(S.P + (long)m2.x * HH + c2);
      ushort2 p3 = *reinterpret_cast<const ushort2*>(S.P + (long)m3.x * HH + c2);
      float e0x = bf2f(m0.y), e0y = bf2f(m0.z), e0z = bf2f(m0.w);
      float e1x = bf2f(m1.y), e1y = bf2f(m1.z), e1z = bf2f(m1.w);
      float e2x = bf2f(m2.y), e2y = bf2f(m2.z), e2z = bf2f(m2.w);
      float e3x = bf2f(m3.y), e3y = bf2f(m3.z), e3z = bf2f(m3.w);
      aA0 += fmaxf(bf2f(p0.x) + qA + e0x * wcA0 + e0y * wcA1 + e0z * wcA2, 0.f);
      aB0 += fmaxf(bf2f(p0.y) + qB + e0x * wcB0 + e0y * wcB1 + e0z * wcB2, 0.f);
      aA1 += fmaxf(bf2f(p1.x) + qA + e1x * wcA0 + e1y * wcA1 + e1z * wcA2, 0.f);
      aB1 += fmaxf(bf2f(p1.y) + qB + e1x * wcB0 + e1y * wcB1 + e1z * wcB2, 0.f);
      aA0 += fmaxf(bf2f(p2.x) + qA + e2x * wcA0 + e2y * wcA1 + e2z * wcA2, 0.f);
      aB0 += fmaxf(bf2f(p2.y) + qB + e2x * wcB0 + e2y * wcB1 + e2z * wcB2, 0.f);
      aA1 += fmaxf(bf2f(p3.x) + qA + e3x * wcA0 + e3y * wcA1 + e3z * wcA2, 0.f);
      aB1 += fmaxf(bf2f(p3.y) + qB + e3x * wcB0 + e3y * wcB1 + e3z * wcB2, 0.f);
    }
    for (; i < len; ++i) {
      ushort4 m0 = ep[i];
      ushort2 p0 = *reinterpret_cast<const ushort2*>(S.P + (long)m0.x * HH + c2);
      float e0x = bf2f(m0.y), e0y = bf2f(m0.z), e0z = bf2f(m0.w);
      aA0 += fmaxf(bf2f(p0.x) + qA + e0x * wcA0 + e0y * wcA1 + e0z * wcA2, 0.f);
      aB0 += fmaxf(bf2f(p0.y) + qB + e0x * wcB0 + e0y * wcB1 + e0z * wcB2, 0.f);
    }
  }
  *reinterpret_cast<ushort2*>(S.hag + (long)dst * HH + c2) =
      make_ushort2(f2bf(aA0 + aA1), f2bf(aB0 + aB1));
}

// ---- msg kernel: M_s = bf16(hagg_s @ W2_s + deg_s*b2_s) ----
struct MsgScale {
  const unsigned short* H; const unsigned short* W2s; const float* b2; const int* deg;
  unsigned short* M;
};
struct MsgParams { MsgScale s[3]; };
__global__ __launch_bounds__(256) void msg_kernel(MsgParams prm) {
  const int bid = blockIdx.x;
  const int si = bid % 3;
  const int n0 = (bid / 3) * 64;
  const MsgScale S = prm.s[si];
  const int t = threadIdx.x;
  const int wave = t >> 6, lane = t & 63;
  const int lr = lane & 15, lgp = lane >> 4;
  const int arow = n0 + wave * 16 + lr;
  const bool aok = arow < NN;
  f32x4 acc[8];
#pragma unroll
  for (int nt = 0; nt < 8; ++nt) acc[nt] = (f32x4){0.f, 0.f, 0.f, 0.f};
#pragma unroll
  for (int kt = 0; kt < 4; ++kt) {
    bf16x8 a = (bf16x8){0, 0, 0, 0, 0, 0, 0, 0};
    if (aok)
      a = *reinterpret_cast<const bf16x8*>(S.H + (long)arow * HH + kt * 32 + lgp * 8);
#pragma unroll
    for (int nt = 0; nt < 8; ++nt)
      acc[nt] = __builtin_amdgcn_mfma_f32_16x16x32_bf16(
          a, bfrag(S.W2s, kt, nt, lane), acc[nt], 0, 0, 0);
  }
#pragma unroll
  for (int nt = 0; nt < 8; ++nt) {
    int col = nt * 16 + lr;
    float bv = S.b2[col];
#pragma unroll
    for (int r = 0; r < 4; ++r) {
      int row = n0 + wave * 16 + lgp * 4 + r;
      if (row < NN) {
        float dg = (float)S.deg[row];
        S.M[(long)row * HH + col] = f2bf(acc[nt][r] + dg * bv);
      }
    }
  }
}

// ---- node kernel: K=512 streaming GEMM with double-buffered LDS B-staging ----
__global__ __launch_bounds__(256) void node_kernel(
    const float* __restrict__ x, const unsigned short* __restrict__ xb,
    const unsigned short* __restrict__ Ml, const unsigned short* __restrict__ Mm,
    const unsigned short* __restrict__ Mg,
    const unsigned short* __restrict__ Wg, const unsigned short* __restrict__ Wu1,
    const unsigned short* __restrict__ Wu2,
    const float* __restrict__ bg, const float* __restrict__ bu1, const float* __restrict__ bu2,
    const float* __restrict__ gamma, const float* __restrict__ beta,
    float* __restrict__ out) {
  __shared__ unsigned short smem[2][8192];
  const int t = threadIdx.x;
  const int n0 = blockIdx.x * 64;
  const int wave = t >> 6, lane = t & 63;
  const int lr = lane & 15, lgp = lane >> 4;
  const int arow = n0 + wave * 16 + lr;
  const bool aok = arow < NN;

  f32x4 accG[8], accH[8];
#pragma unroll
  for (int nt = 0; nt < 8; ++nt) {
    accG[nt] = (f32x4){0.f, 0.f, 0.f, 0.f};
    accH[nt] = (f32x4){0.f, 0.f, 0.f, 0.f};
  }

  {
    ushort8 g0 = *reinterpret_cast<const ushort8*>(Wg + t * 8);
    ushort8 g1 = *reinterpret_cast<const ushort8*>(Wg + 2048 + t * 8);
    ushort8 u0 = *reinterpret_cast<const ushort8*>(Wu1 + t * 8);
    ushort8 u1 = *reinterpret_cast<const ushort8*>(Wu1 + 2048 + t * 8);
    *reinterpret_cast<ushort8*>(&smem[0][t * 8]) = g0;
    *reinterpret_cast<ushort8*>(&smem[0][2048 + t * 8]) = g1;
    *reinterpret_cast<ushort8*>(&smem[0][4096 + t * 8]) = u0;
    *reinterpret_cast<ushort8*>(&smem[0][6144 + t * 8]) = u1;
  }

#pragma unroll
  for (int kt = 0; kt < 16; ++kt) {
    const int cb = kt & 1, nb = cb ^ 1;
    __syncthreads();
    ushort8 ng0, ng1, nu0, nu1;
    if (kt < 15) {
      const unsigned short* gG = Wg + (kt + 1) * 4096;
      const unsigned short* gU = Wu1 + (kt + 1) * 4096;
      ng0 = *reinterpret_cast<const ushort8*>(gG + t * 8);
      ng1 = *reinterpret_cast<const ushort8*>(gG + 2048 + t * 8);
      nu0 = *reinterpret_cast<const ushort8*>(gU + t * 8);
      nu1 = *reinterpret_cast<const ushort8*>(gU + 2048 + t * 8);
    }
    const unsigned short* S = (kt < 4) ? xb : (kt < 8) ? Ml : (kt < 12) ? Mm : Mg;
    int cbase = ((kt & 3) << 5) + (lgp << 3);
    bf16x8 a = (bf16x8){0, 0, 0, 0, 0, 0, 0, 0};
    if (aok) a = *reinterpret_cast<const bf16x8*>(S + (long)arow * HH + cbase);
#pragma unroll
    for (int nt = 0; nt < 8; ++nt) {
      bf16x8 bgf = *reinterpret_cast<const bf16x8*>(&smem[cb][nt * 512 + lane * 8]);
      accG[nt] = __builtin_amdgcn_mfma_f32_16x16x32_bf16(a, bgf, accG[nt], 0, 0, 0);
      bf16x8 buf_ = *reinterpret_cast<const bf16x8*>(&smem[cb][4096 + nt * 512 + lane * 8]);
      accH[nt] = __builtin_amdgcn_mfma_f32_16x16x32_bf16(a, buf_, accH[nt], 0, 0, 0);
    }
    if (kt < 15) {
      *reinterpret_cast<ushort8*>(&smem[nb][t * 8]) = ng0;
      *reinterpret_cast<ushort8*>(&smem[nb][2048 + t * 8]) = ng1;
      *reinterpret_cast<ushort8*>(&smem[nb][4096 + t * 8]) = nu0;
      *reinterpret_cast<ushort8*>(&smem[nb][6144 + t * 8]) = nu1;
    }
  }
  __syncthreads();

  unsigned short (*Hs)[136] = reinterpret_cast<unsigned short(*)[136]>(&smem[0][0]);

#pragma unroll
  for (int nt = 0; nt < 8; ++nt) {
    int col = nt * 16 + lr;
    float bgv = bg[col], bhv = bu1[col];
#pragma unroll
    for (int r = 0; r < 4; ++r) {
      float g = 1.f / (1.f + __expf(-(accG[nt][r] + bgv)));
      accG[nt][r] = g;
      float h = fmaxf(accH[nt][r] + bhv, 0.f);
      Hs[wave * 16 + lgp * 4 + r][col] = f2bf(h);
    }
  }

  f32x4 accU[8];
#pragma unroll
  for (int nt = 0; nt < 8; ++nt) accU[nt] = (f32x4){0.f, 0.f, 0.f, 0.f};
#pragma unroll
  for (int kt = 0; kt < 4; ++kt) {
    bf16x8 a = *reinterpret_cast<const bf16x8*>(&Hs[wave * 16 + lr][kt * 32 + lgp * 8]);
#pragma unroll
    for (int nt = 0; nt < 8; ++nt) {
      accU[nt] = __builtin_amdgcn_mfma_f32_16x16x32_bf16(a, bfrag(Wu2, kt, nt, lane), accU[nt], 0, 0, 0);
    }
  }

#pragma unroll
  for (int nt = 0; nt < 8; ++nt) {
    int col = nt * 16 + lr;
    float b2v = bu2[col];
#pragma unroll
    for (int r = 0; r < 4; ++r) {
      int row = n0 + wave * 16 + lgp * 4 + r;
      float xv = (row < NN) ? x[(long)row * HH + col] : 0.f;
      float u = accU[nt][r] + b2v;
      float g = accG[nt][r];
      accU[nt][r] = g * u + (1.f - g) * xv;
    }
  }

#pragma unroll
  for (int r = 0; r < 4; ++r) {
    int row = n0 + wave * 16 + lgp * 4 + r;
    float s = 0.f;
#pragma unroll
    for (int nt = 0; nt < 8; ++nt) s += accU[nt][r];
    s += __shfl_xor(s, 1, 64);
    s += __shfl_xor(s, 2, 64);
    s += __shfl_xor(s, 4, 64);
    s += __shfl_xor(s, 8, 64);
    float mu = s * (1.f / 128.f);
    float qv = 0.f;
#pragma unroll
    for (int nt = 0; nt < 8; ++nt) {
      float d = accU[nt][r] - mu;
      qv += d * d;
    }
    qv += __shfl_xor(qv, 1, 64);
    qv += __shfl_xor(qv, 2, 64);
    qv += __shfl_xor(qv, 4, 64);
    qv += __shfl_xor(qv, 8, 64);
    float rs = rsqrtf(qv * (1.f / 128.f) + 1e-5f);
    if (row < NN) {
#pragma unroll
      for (int nt = 0; nt < 8; ++nt) {
        int col = nt * 16 + lr;
        out[(long)row * HH + col] = (accU[nt][r] - mu) * rs * gamma[col] + beta[col];
      }
    }
  }
}

extern "C" void kernel_launch(void* const* d_in, const int* in_sizes, int n_in,
                              void* d_out, int out_size, void* d_ws, size_t ws_size,
                              hipStream_t stream) {
  const float* x = (const float*)d_in[0];
  const int* ei_l = (const int*)d_in[1];
  const float* ea_l = (const float*)d_in[2];
  const int* ei_m = (const int*)d_in[3];
  const float* ea_m = (const float*)d_in[4];
  const int* ei_g = (const int*)d_in[5];
  const float* ea_g = (const float*)d_in[6];
  const float* Wa1 = (const float*)d_in[7];
  const float* ba1 = (const float*)d_in[8];
  const float* Wa2 = (const float*)d_in[9];
  const float* ba2 = (const float*)d_in[10];
  const float* Wb1 = (const float*)d_in[11];
  const float* bb1 = (const float*)d_in[12];
  const float* Wb2 = (const float*)d_in[13];
  const float* bb2 = (const float*)d_in[14];
  const float* Wc1 = (const float*)d_in[15];
  const float* bc1 = (const float*)d_in[16];
  const float* Wc2 = (const float*)d_in[17];
  const float* bc2 = (const float*)d_in[18];
  const float* Wg = (const float*)d_in[19];
  const float* bg = (const float*)d_in[20];
  const float* Wu1 = (const float*)d_in[21];
  const float* bu1 = (const float*)d_in[22];
  const float* Wu2 = (const float*)d_in[23];
  const float* bu2 = (const float*)d_in[24];
  const float* gamma = (const float*)d_in[25];
  const float* beta = (const float*)d_in[26];

  const int El = in_sizes[1] / 2;
  const int Em = in_sizes[3] / 2;
  const int Eg = in_sizes[5] / 2;
  const int Etot = El + Em + Eg;

  // Workspace layout (hagg bf16)
  unsigned short* wp = (unsigned short*)d_ws;
  unsigned short* hl = wp; wp += (size_t)NN * HH;
  unsigned short* hm = wp; wp += (size_t)NN * HH;
  unsigned short* hg = wp; wp += (size_t)NN * HH;
  unsigned short* W1a_a = wp; wp += 128 * 128;
  unsigned short* W1b_a = wp; wp += 128 * 128;
  unsigned short* W2_a  = wp; wp += 128 * 128;
  unsigned short* W1a_b = wp; wp += 128 * 128;
  unsigned short* W1b_b = wp; wp += 128 * 128;
  unsigned short* W2_b  = wp; wp += 128 * 128;
  unsigned short* W1a_c = wp; wp += 128 * 128;
  unsigned short* W1b_c = wp; wp += 128 * 128;
  unsigned short* W2_c  = wp; wp += 128 * 128;
  unsigned short* Wu2_s = wp; wp += 128 * 128;
  unsigned short* Wg_s  = wp; wp += 512 * 128;
  unsigned short* Wu1_s = wp; wp += 512 * 128;
  unsigned short* xb  = wp; wp += (size_t)NN * HH;
  unsigned short* P_l = wp; wp += (size_t)NN * HH;
  unsigned short* Q_l = wp; wp += (size_t)NN * HH;
  unsigned short* P_m = wp; wp += (size_t)NN * HH;
  unsigned short* Q_m = wp; wp += (size_t)NN * HH;
  unsigned short* P_g = wp; wp += (size_t)NN * HH;
  unsigned short* Q_g = wp; wp += (size_t)NN * HH;
  unsigned short* M_l = P_l;   // alias (P dead after edge_kernel)
  unsigned short* M_m = P_m;
  unsigned short* M_g = P_g;
  int* ip = (int*)wp;
  int* cnt    = ip; ip += 3 * NN;   // degrees (kept)
  int* offs   = ip; ip += 3 * NN;   // scanA scratch
  int* rowptr = ip; ip += 3 * NN;   // exclusive scan (kept)
  int* bsum   = ip; ip += 256;
  int* rk     = ip; ip += Etot;     // per-edge rank within dst segment
  size_t off16 = ((size_t)((char*)ip - (char*)d_ws) + 15) & ~(size_t)15;
  ushort4* sed = (ushort4*)((char*)d_ws + off16);   // Etot packed 8B records

  hipMemsetAsync(cnt, 0, 3 * NN * sizeof(int), stream);

  // prep: cvt_x ∪ swz ∪ hist+rank (one launch)
  PrepParams pp;
  pp.x = x; pp.xb = xb; pp.total8 = NN * HH / 8;
  pp.cvtBlocks = (pp.total8 + 255) / 256;
  pp.swz.src[0] = Wa1;            pp.swz.dst[0] = W1a_a;
  pp.swz.src[1] = Wa1 + 128*128;  pp.swz.dst[1] = W1b_a;
  pp.swz.src[2] = Wa2;            pp.swz.dst[2] = W2_a;
  pp.swz.src[3] = Wb1;            pp.swz.dst[3] = W1a_b;
  pp.swz.src[4] = Wb1 + 128*128;  pp.swz.dst[4] = W1b_b;
  pp.swz.src[5] = Wb2;            pp.swz.dst[5] = W2_b;
  pp.swz.src[6] = Wc1;            pp.swz.dst[6] = W1a_c;
  pp.swz.src[7] = Wc1 + 128*128;  pp.swz.dst[7] = W1b_c;
  pp.swz.src[8] = Wc2;            pp.swz.dst[8] = W2_c;
  pp.swz.src[9] = Wu2;            pp.swz.dst[9] = Wu2_s;
  pp.swz.src[10] = Wg;            pp.swz.dst[10] = Wg_s;
  pp.swz.src[11] = Wu1;           pp.swz.dst[11] = Wu1_s;
  pp.swzBlocks = 640 + 512;
  pp.eiL = ei_l; pp.eiM = ei_m; pp.eiG = ei_g;
  pp.El = El; pp.Em = Em; pp.Eg = Eg; pp.cnt = cnt; pp.rk = rk;
  const int histBlocks = (Etot + 255) / 256;
  prep_kernel<<<pp.cvtBlocks + pp.swzBlocks + histBlocks, 256, 0, stream>>>(pp);

  // scan (exclusive, into rowptr)
  const int n3 = 3 * NN;
  const int nblkA = (n3 + 1023) / 1024;
  scanA_kernel<<<nblkA, 1024, 0, stream>>>(cnt, offs, bsum, n3);
  scanB_kernel<<<1, 256, 0, stream>>>(bsum, nblkA);
  scanC_kernel<<<nblkA, 1024, 0, stream>>>(offs, rowptr, bsum, n3);

  // fused scatter ∪ pq (scatter atomic-free)
  SpqParams sp;
  sp.eiL = ei_l; sp.eiM = ei_m; sp.eiG = ei_g;
  sp.eaL = ea_l; sp.eaM = ea_m; sp.eaG = ea_g;
  sp.El = El; sp.Em = Em; sp.Eg = Eg;
  sp.rowptr = rowptr; sp.rk = rk; sp.sed = sed;
  sp.scatterBlocks = (Etot + 255) / 256;
  sp.xb = xb;
  sp.pq.Wswz[0] = W1a_a; sp.pq.bias[0] = nullptr; sp.pq.out[0] = P_l;
  sp.pq.Wswz[1] = W1b_a; sp.pq.bias[1] = ba1;     sp.pq.out[1] = Q_l;
  sp.pq.Wswz[2] = W1a_b; sp.pq.bias[2] = nullptr; sp.pq.out[2] = P_m;
  sp.pq.Wswz[3] = W1b_b; sp.pq.bias[3] = bb1;     sp.pq.out[3] = Q_m;
  sp.pq.Wswz[4] = W1a_c; sp.pq.bias[4] = nullptr; sp.pq.out[4] = P_g;
  sp.pq.Wswz[5] = W1b_c; sp.pq.bias[5] = bc1;     sp.pq.out[5] = Q_g;
  const int NB = (NN + 63) / 64;
  spq_kernel<<<sp.scatterBlocks + NB * 6, 256, 0, stream>>>(sp);

  // Edge pass: one wave per dst, 8B records, plain bf16 stores
  EParams2 ep;
  ep.s[0] = {P_l, Q_l, Wa1 + 256 * 128, hl};
  ep.s[1] = {P_m, Q_m, Wb1 + 256 * 128, hm};
  ep.s[2] = {P_g, Q_g, Wc1 + 256 * 128, hg};
  ep.sed = sed; ep.rowptr = rowptr; ep.cnt = cnt;
  edge_kernel<<<(3 * NN + 3) / 4, 256, 0, stream>>>(ep);

  // Msg pass: M_s = bf16(hagg_s @ W2_s + deg*b2_s)
  MsgParams mp;
  mp.s[0] = {hl, W2_a, ba2, cnt,          M_l};
  mp.s[1] = {hm, W2_b, bb2, cnt + NN,     M_m};
  mp.s[2] = {hg, W2_c, bc2, cnt + 2 * NN, M_g};
  msg_kernel<<<3 * NB, 256, 0, stream>>>(mp);

  // Node update + LayerNorm (LDS-staged B, double-buffered)
  node_kernel<<<NB, 256, 0, stream>>>(x, xb, M_l, M_m, M_g, Wg_s, Wu1_s, Wu2_s,
                                      bg, bu1, bu2, gamma, beta, (float*)d_out);
}